// Round 1
// baseline (6348.558 us; speedup 1.0000x reference)
//
#include <hip/hip_runtime.h>
#include <math.h>

#define RES   48
#define WS    4
#define SSH   2
#define DIM   96
#define HEADS 3
#define HD    32
#define NTOK  64
#define NWAX  12
#define NWIN  (NWAX*NWAX*NWAX)   // 1728

__device__ __forceinline__ int region(int g) {
    return (g < RES - WS) ? 0 : ((g < RES - SSH) ? 1 : 2);
}

// ---------------- CPB table: hidden(512) relu -> 3 heads, per 343 coords ----------------
__global__ void cpb_table_kernel(const float* __restrict__ w1, const float* __restrict__ b1,
                                 const float* __restrict__ w2, float* __restrict__ tbl) {
    __shared__ float hid[512];
    int ti = blockIdx.x;                 // 0..342
    int a = ti / 49, b = (ti / 7) % 7, c = ti % 7;
    float comp[3] = {(float)(a - 3), (float)(b - 3), (float)(c - 3)};
    float f[3];
    #pragma unroll
    for (int k = 0; k < 3; ++k) {
        float u = (comp[k] / 3.0f) * 8.0f;
        float s = (u > 0.f) ? 1.f : ((u < 0.f) ? -1.f : 0.f);
        f[k] = s * log2f(fabsf(u) + 1.0f) * (1.0f / 3.0f);
    }
    for (int j = threadIdx.x; j < 512; j += blockDim.x) {
        float acc = b1[j] + f[0]*w1[j*3+0] + f[1]*w1[j*3+1] + f[2]*w1[j*3+2];
        hid[j] = fmaxf(acc, 0.f);
    }
    __syncthreads();
    int tid = threadIdx.x;
    if (tid < 192) {
        int h = tid >> 6, lane = tid & 63;
        float p = 0.f;
        for (int j = lane; j < 512; j += 64) p += w2[h*512 + j] * hid[j];
        #pragma unroll
        for (int off = 32; off; off >>= 1) p += __shfl_down(p, off, 64);
        if (lane == 0) tbl[ti*3 + h] = p;
    }
}

// ---------------- rpb[h][i][j] = 16*sigmoid(tbl[rpi(i,j)][h]) ----------------
__global__ void rpb_kernel(const float* __restrict__ tbl, float* __restrict__ rpb) {
    int bi = blockIdx.x;                 // h*64 + i
    int h = bi >> 6, i = bi & 63;
    int j = threadIdx.x;                 // 0..63
    int hi = i >> 4, wi = (i >> 2) & 3, di = i & 3;
    int hj = j >> 4, wj = (j >> 2) & 3, dj = j & 3;
    int idx = (hi - hj + 3)*49 + (wi - wj + 3)*7 + (di - dj + 3);
    float v = tbl[idx*3 + h];
    rpb[(h*64 + i)*64 + j] = 16.0f / (1.0f + expf(-v));
}

// ---------------- window attention: qkv, cosine attn, online softmax, proj ----------------
__global__ __launch_bounds__(256)
void attn_kernel(const float* __restrict__ x, const float* __restrict__ qkv_w,
                 const float* __restrict__ q_bias, const float* __restrict__ v_bias,
                 const float* __restrict__ logit_scale,
                 const float* __restrict__ proj_w, const float* __restrict__ proj_b,
                 const float* __restrict__ rpb, float* __restrict__ y) {
    __shared__ float kv_s[NTOK * 193];   // cols 0..95 = k (head-major), 96..191 = v; pad->193
    __shared__ int xbase[NTOK];
    __shared__ int cnt[NTOK];

    int tid = threadIdx.x;
    int wid = blockIdx.x;
    int b   = wid / NWIN;
    int rem = wid % NWIN;
    int wh = rem / (NWAX*NWAX);
    int ww = (rem / NWAX) % NWAX;
    int wd = rem % NWAX;

    if (tid < NTOK) {
        int t = tid;
        int lh = t >> 4, lw = (t >> 2) & 3, ld = t & 3;
        int gh = wh*WS + lh, gw = ww*WS + lw, gd = wd*WS + ld;
        int sh = (gh + SSH) % RES, sw = (gw + SSH) % RES, sd = (gd + SSH) % RES;
        xbase[t] = (((b*RES + sh)*RES + sw)*RES + sd)*DIM;
        cnt[t]   = region(gh)*9 + region(gw)*3 + region(gd);
    }
    __syncthreads();

    // K,V GEMM: outputs (t, o) with o in [0,192); qkv_w row = 96+o; lanes vary t -> weight broadcast
    for (int idx = tid; idx < NTOK*192; idx += 256) {
        int t = idx & 63, o = idx >> 6;
        const float* w  = qkv_w + (96 + o)*DIM;
        const float* xr = x + xbase[t];
        float acc = (o < 96) ? 0.0f : v_bias[o - 96];
        #pragma unroll 4
        for (int c = 0; c < DIM; ++c) acc = fmaf(xr[c], w[c], acc);
        kv_s[t*193 + o] = acc;
    }
    __syncthreads();

    int h = tid >> 6;     // wave-uniform head
    int i = tid & 63;
    float q[HD];
    float o_[HD];

    if (tid < 192) {
        // normalize k row (h,i) in place
        float kn = 0.f;
        #pragma unroll
        for (int d = 0; d < HD; ++d) { float v = kv_s[i*193 + h*HD + d]; kn += v*v; }
        float kr = 1.0f / fmaxf(sqrtf(kn), 1e-12f);
        #pragma unroll
        for (int d = 0; d < HD; ++d) kv_s[i*193 + h*HD + d] *= kr;

        // q row (h,i) in registers
        const float* xr = x + xbase[i];
        #pragma unroll
        for (int d = 0; d < HD; ++d) q[d] = q_bias[h*HD + d];
        for (int c = 0; c < DIM; ++c) {
            float xv = xr[c];
            #pragma unroll
            for (int d = 0; d < HD; ++d) q[d] = fmaf(xv, qkv_w[(h*HD + d)*DIM + c], q[d]);
        }
        float qn = 0.f;
        #pragma unroll
        for (int d = 0; d < HD; ++d) qn += q[d]*q[d];
        float sc = expf(fminf(logit_scale[h], 4.605170185988092f));
        float qr = sc / fmaxf(sqrtf(qn), 1e-12f);
        #pragma unroll
        for (int d = 0; d < HD; ++d) q[d] *= qr;
    }
    __syncthreads();

    if (tid < 192) {
        const float* rp = rpb + (h*64 + i)*64;
        int ci = cnt[i];
        float m = -1e30f, l = 0.f;
        #pragma unroll
        for (int d = 0; d < HD; ++d) o_[d] = 0.f;
        for (int j = 0; j < NTOK; ++j) {
            float s = 0.f;
            #pragma unroll
            for (int d = 0; d < HD; ++d) s = fmaf(q[d], kv_s[j*193 + h*HD + d], s);
            s += rp[j];
            if (ci != cnt[j]) s -= 100.0f;
            float mn   = fmaxf(m, s);
            float corr = expf(m - mn);
            float e    = expf(s - mn);
            l = l*corr + e;
            #pragma unroll
            for (int d = 0; d < HD; ++d)
                o_[d] = fmaf(e, kv_s[j*193 + 96 + h*HD + d], o_[d]*corr);
            m = mn;
        }
        float rinv = 1.0f / l;
        #pragma unroll
        for (int d = 0; d < HD; ++d) o_[d] *= rinv;
    }
    __syncthreads();           // everyone done reading k region
    if (tid < 192) {
        #pragma unroll
        for (int d = 0; d < HD; ++d) kv_s[i*193 + h*HD + d] = o_[d];
    }
    __syncthreads();

    // proj: y[t][c] = proj_b[c] + sum_k o[t][k]*proj_w[c][k]; write to global at read position
    for (int idx = tid; idx < NTOK*DIM; idx += 256) {
        int t = idx / DIM, c = idx % DIM;
        const float* w = proj_w + c*DIM;
        const float* orow = kv_s + t*193;
        float acc = proj_b[c];
        #pragma unroll 4
        for (int k2 = 0; k2 < DIM; ++k2) acc = fmaf(orow[k2], w[k2], acc);
        y[xbase[t] + c] = acc;
    }
}

// ---------------- fused LN + residual + MLP + LN + residual ----------------
__global__ __launch_bounds__(256)
void mlp_kernel(const float* __restrict__ x, const float* __restrict__ yin,
                const float* __restrict__ g1, const float* __restrict__ b1,
                const float* __restrict__ fc1_w, const float* __restrict__ fc1_b,
                const float* __restrict__ fc2_w, const float* __restrict__ fc2_b,
                const float* __restrict__ g2, const float* __restrict__ b2,
                float* __restrict__ out) {
    const int TOK = 32;
    __shared__ float x1[TOK * 97];       // padded
    __shared__ float hbuf[TOK * 385];    // fc1 outputs; also staging w/ stride 97
    __shared__ float mu_s[TOK], rs_s[TOK];

    int tid = threadIdx.x;
    long tok0 = (long)blockIdx.x * TOK;
    const float* ybase = yin + tok0*DIM;
    const float* xbase = x   + tok0*DIM;

    // stage attention output (stride-97 to dodge bank conflicts in LN)
    for (int idx = tid; idx < TOK*DIM; idx += 256) {
        int t = idx / DIM, c = idx % DIM;
        hbuf[t*97 + c] = ybase[idx];
    }
    __syncthreads();
    if (tid < TOK) {
        float mu = 0.f;
        for (int c = 0; c < DIM; ++c) mu += hbuf[tid*97 + c];
        mu *= (1.0f/DIM);
        float var = 0.f;
        for (int c = 0; c < DIM; ++c) { float d = hbuf[tid*97 + c] - mu; var += d*d; }
        var *= (1.0f/DIM);
        mu_s[tid] = mu;
        rs_s[tid] = rsqrtf(var + 1e-5f);
    }
    __syncthreads();
    for (int idx = tid; idx < TOK*DIM; idx += 256) {
        int t = idx / DIM, c = idx % DIM;
        x1[t*97 + c] = xbase[idx] + (hbuf[t*97 + c] - mu_s[t])*rs_s[t]*g1[c] + b1[c];
    }
    __syncthreads();

    // fc1 + exact gelu: lanes vary t (weight row broadcast within wave)
    for (int idx = tid; idx < TOK*384; idx += 256) {
        int t = idx & 31, o = idx >> 5;
        const float* w = fc1_w + o*DIM;
        const float* xr = x1 + t*97;
        float acc = fc1_b[o];
        #pragma unroll 4
        for (int c = 0; c < DIM; ++c) acc = fmaf(xr[c], w[c], acc);
        hbuf[t*385 + o] = 0.5f * acc * (1.0f + erff(acc * 0.70710678118654752f));
    }
    __syncthreads();

    // fc2 into registers
    float r[12];
    #pragma unroll
    for (int n = 0; n < 12; ++n) {
        int idx = tid + n*256;           // < 3072
        int t = idx & 31, c = idx >> 5;
        const float* w  = fc2_w + c*384;
        const float* hr = hbuf + t*385;
        float acc = fc2_b[c];
        #pragma unroll 4
        for (int o = 0; o < 384; ++o) acc = fmaf(hr[o], w[o], acc);
        r[n] = acc;
    }
    __syncthreads();
    #pragma unroll
    for (int n = 0; n < 12; ++n) {
        int idx = tid + n*256;
        int t = idx & 31, c = idx >> 5;
        hbuf[t*97 + c] = r[n];
    }
    __syncthreads();
    if (tid < TOK) {
        float mu = 0.f;
        for (int c = 0; c < DIM; ++c) mu += hbuf[tid*97 + c];
        mu *= (1.0f/DIM);
        float var = 0.f;
        for (int c = 0; c < DIM; ++c) { float d = hbuf[tid*97 + c] - mu; var += d*d; }
        var *= (1.0f/DIM);
        mu_s[tid] = mu;
        rs_s[tid] = rsqrtf(var + 1e-5f);
    }
    __syncthreads();
    for (int idx = tid; idx < TOK*DIM; idx += 256) {
        int t = idx / DIM, c = idx % DIM;
        out[tok0*DIM + idx] = x1[t*97 + c] + (hbuf[t*97 + c] - mu_s[t])*rs_s[t]*g2[c] + b2[c];
    }
}

extern "C" void kernel_launch(void* const* d_in, const int* in_sizes, int n_in,
                              void* d_out, int out_size, void* d_ws, size_t ws_size,
                              hipStream_t stream) {
    const float* x      = (const float*)d_in[0];
    const float* qkv_w  = (const float*)d_in[1];
    const float* q_bias = (const float*)d_in[2];
    const float* v_bias = (const float*)d_in[3];
    const float* lscale = (const float*)d_in[4];
    const float* cpb_w1 = (const float*)d_in[5];
    const float* cpb_b1 = (const float*)d_in[6];
    const float* cpb_w2 = (const float*)d_in[7];
    const float* proj_w = (const float*)d_in[8];
    const float* proj_b = (const float*)d_in[9];
    const float* n1g    = (const float*)d_in[10];
    const float* n1b    = (const float*)d_in[11];
    const float* fc1_w  = (const float*)d_in[12];
    const float* fc1_b  = (const float*)d_in[13];
    const float* fc2_w  = (const float*)d_in[14];
    const float* fc2_b  = (const float*)d_in[15];
    const float* n2g    = (const float*)d_in[16];
    const float* n2b    = (const float*)d_in[17];
    float* out = (float*)d_out;

    float* tbl = (float*)d_ws;               // 343*3 floats
    float* rpb = (float*)d_ws + 2048;        // 3*64*64 floats

    cpb_table_kernel<<<343, 256, 0, stream>>>(cpb_w1, cpb_b1, cpb_w2, tbl);
    rpb_kernel<<<192, 64, 0, stream>>>(tbl, rpb);
    attn_kernel<<<2*NWIN, 256, 0, stream>>>(x, qkv_w, q_bias, v_bias, lscale,
                                            proj_w, proj_b, rpb, out);
    mlp_kernel<<<(2*RES*RES*RES)/32, 256, 0, stream>>>(x, out, n1g, n1b,
                                                       fc1_w, fc1_b, fc2_w, fc2_b,
                                                       n2g, n2b, out);
}

// Round 2
// 1590.389 us; speedup vs baseline: 3.9918x; 3.9918x over previous
//
#include <hip/hip_runtime.h>
#include <math.h>

#define RES   48
#define WS    4
#define SSH   2
#define DIM   96
#define HEADS 3
#define HD    32
#define NTOK  64
#define NWAX  12
#define NWIN  (NWAX*NWAX*NWAX)   // 1728

#define XS_STRIDE 100   // dwords: 16B-quad stride 25 (odd) -> conflict-free b128
#define KV_STRIDE 196   // dwords: 16B-quad stride 49 (odd) -> conflict-free b128

__device__ __forceinline__ int region(int g) {
    return (g < RES - WS) ? 0 : ((g < RES - SSH) ? 1 : 2);
}

// ---------------- CPB table: hidden(512) relu -> 3 heads, per 343 coords ----------------
__global__ void cpb_table_kernel(const float* __restrict__ w1, const float* __restrict__ b1,
                                 const float* __restrict__ w2, float* __restrict__ tbl) {
    __shared__ float hid[512];
    int ti = blockIdx.x;                 // 0..342
    int a = ti / 49, b = (ti / 7) % 7, c = ti % 7;
    float comp[3] = {(float)(a - 3), (float)(b - 3), (float)(c - 3)};
    float f[3];
    #pragma unroll
    for (int k = 0; k < 3; ++k) {
        float u = (comp[k] / 3.0f) * 8.0f;
        float s = (u > 0.f) ? 1.f : ((u < 0.f) ? -1.f : 0.f);
        f[k] = s * log2f(fabsf(u) + 1.0f) * (1.0f / 3.0f);
    }
    for (int j = threadIdx.x; j < 512; j += blockDim.x) {
        float acc = b1[j] + f[0]*w1[j*3+0] + f[1]*w1[j*3+1] + f[2]*w1[j*3+2];
        hid[j] = fmaxf(acc, 0.f);
    }
    __syncthreads();
    int tid = threadIdx.x;
    if (tid < 192) {
        int h = tid >> 6, lane = tid & 63;
        float p = 0.f;
        for (int j = lane; j < 512; j += 64) p += w2[h*512 + j] * hid[j];
        #pragma unroll
        for (int off = 32; off; off >>= 1) p += __shfl_down(p, off, 64);
        if (lane == 0) tbl[ti*3 + h] = p;
    }
}

// ---------------- rpbT[h][j][i] = 16*sigmoid(tbl[rpi(i,j)][h])  (TRANSPOSED) ----------------
__global__ void rpb_kernel(const float* __restrict__ tbl, float* __restrict__ rpbT) {
    int bi = blockIdx.x;                 // h*64 + i
    int h = bi >> 6, i = bi & 63;
    int j = threadIdx.x;                 // 0..63
    int hi = i >> 4, wi = (i >> 2) & 3, di = i & 3;
    int hj = j >> 4, wj = (j >> 2) & 3, dj = j & 3;
    int idx = (hi - hj + 3)*49 + (wi - wj + 3)*7 + (di - dj + 3);
    float v = tbl[idx*3 + h];
    rpbT[(h*64 + j)*64 + i] = 16.0f / (1.0f + expf(-v));
}

// ---------------- window attention ----------------
__global__ __launch_bounds__(256, 2)
void attn_kernel(const float* __restrict__ x, const float* __restrict__ qkv_w,
                 const float* __restrict__ q_bias, const float* __restrict__ v_bias,
                 const float* __restrict__ logit_scale,
                 const float* __restrict__ proj_w, const float* __restrict__ proj_b,
                 const float* __restrict__ rpbT, float* __restrict__ y) {
    __shared__ float x_s[NTOK * XS_STRIDE];    // 25.6 KB (staged x; later proj-out staging)
    __shared__ float kv_s[NTOK * KV_STRIDE];   // 50.2 KB (k: 0..95, v: 96..191)
    __shared__ float knorm_s[192];
    __shared__ int xbase[NTOK];
    __shared__ int cnt[NTOK];

    int tid  = threadIdx.x;
    int lane = tid & 63;
    int wv   = __builtin_amdgcn_readfirstlane(tid >> 6);

    int wid = blockIdx.x;
    int b   = wid / NWIN;
    int rem = wid - b*NWIN;
    int wh = rem / (NWAX*NWAX);
    int ww = (rem / NWAX) % NWAX;
    int wd = rem % NWAX;

    if (tid < NTOK) {
        int t = tid;
        int lh = t >> 4, lw = (t >> 2) & 3, ld = t & 3;
        int gh = wh*WS + lh, gw = ww*WS + lw, gd = wd*WS + ld;
        int sh = (gh + SSH) % RES, sw = (gw + SSH) % RES, sd = (gd + SSH) % RES;
        xbase[t] = (((b*RES + sh)*RES + sw)*RES + sd)*DIM;
        cnt[t]   = region(gh)*9 + region(gw)*3 + region(gd);
    }
    __syncthreads();

    // stage x rows (coalesced float4 within each 384B row segment)
    for (int idx = tid; idx < NTOK*24; idx += 256) {
        int r = idx / 24, c4 = idx - r*24;
        float4 v = *reinterpret_cast<const float4*>(x + xbase[r] + c4*4);
        *reinterpret_cast<float4*>(&x_s[r*XS_STRIDE + c4*4]) = v;
    }
    __syncthreads();

    // ---- Phase A: K,V GEMM. thread (t=lane, wave wv) computes o = wv*48 + og*8 + r ----
    {
        int t = lane;
        for (int og = 0; og < 6; ++og) {
            int o0 = wv*48 + og*8;
            float acc[8];
            #pragma unroll
            for (int r = 0; r < 8; ++r)
                acc[r] = (o0 + r < 96) ? 0.0f : v_bias[o0 + r - 96];
            for (int c4 = 0; c4 < 24; ++c4) {
                float4 xv = *reinterpret_cast<const float4*>(&x_s[t*XS_STRIDE + c4*4]);
                #pragma unroll
                for (int cc = 0; cc < 4; ++cc) {
                    float xc = (&xv.x)[cc];
                    int c = c4*4 + cc;
                    #pragma unroll
                    for (int r = 0; r < 8; ++r)
                        acc[r] = fmaf(xc, qkv_w[(96 + o0 + r)*DIM + c], acc[r]);
                }
            }
            *reinterpret_cast<float4*>(&kv_s[t*KV_STRIDE + o0])     = make_float4(acc[0],acc[1],acc[2],acc[3]);
            *reinterpret_cast<float4*>(&kv_s[t*KV_STRIDE + o0 + 4]) = make_float4(acc[4],acc[5],acc[6],acc[7]);
        }
    }

    // ---- Phase B: Q GEMM into registers (threads 0..191: wave = head) ----
    float q[HD];
    int h = wv;
    int i = lane;
    if (tid < 192) {
        #pragma unroll
        for (int d = 0; d < HD; ++d) q[d] = q_bias[h*HD + d];
        for (int c4 = 0; c4 < 24; ++c4) {
            float4 xv = *reinterpret_cast<const float4*>(&x_s[i*XS_STRIDE + c4*4]);
            #pragma unroll
            for (int cc = 0; cc < 4; ++cc) {
                float xc = (&xv.x)[cc];
                int c = c4*4 + cc;
                #pragma unroll
                for (int d = 0; d < HD; ++d)
                    q[d] = fmaf(xc, qkv_w[(h*HD + d)*DIM + c], q[d]);
            }
        }
        float qn = 0.f;
        #pragma unroll
        for (int d = 0; d < HD; ++d) qn += q[d]*q[d];
        float sc = expf(fminf(logit_scale[h], 4.605170185988092f));
        float qr = sc / fmaxf(sqrtf(qn), 1e-12f);
        #pragma unroll
        for (int d = 0; d < HD; ++d) q[d] *= qr;
    }
    __syncthreads();   // kv_s fully written

    // ---- Phase C: cosine attention, two-pass softmax ----
    if (tid < 192) {
        // k row norms -> LDS table (k itself stays un-normalized)
        float kn = 0.f;
        #pragma unroll
        for (int d4 = 0; d4 < 8; ++d4) {
            float4 kv = *reinterpret_cast<const float4*>(&kv_s[i*KV_STRIDE + h*HD + d4*4]);
            kn += kv.x*kv.x + kv.y*kv.y + kv.z*kv.z + kv.w*kv.w;
        }
        knorm_s[h*64 + i] = 1.0f / fmaxf(sqrtf(kn), 1e-12f);
        __threadfence_block();

        int ci = cnt[i];
        float sreg[NTOK];
        float m = -1e30f;
        #pragma unroll
        for (int j = 0; j < NTOK; ++j) {
            float s = 0.f;
            #pragma unroll
            for (int d4 = 0; d4 < 8; ++d4) {
                float4 kj = *reinterpret_cast<const float4*>(&kv_s[j*KV_STRIDE + h*HD + d4*4]);
                s = fmaf(q[d4*4+0], kj.x, s);
                s = fmaf(q[d4*4+1], kj.y, s);
                s = fmaf(q[d4*4+2], kj.z, s);
                s = fmaf(q[d4*4+3], kj.w, s);
            }
            s = s * knorm_s[h*64 + j] + rpbT[(h*64 + j)*64 + i];
            if (ci != cnt[j]) s -= 100.0f;
            sreg[j] = s;
            m = fmaxf(m, s);
        }

        float o_[HD];
        #pragma unroll
        for (int d = 0; d < HD; ++d) o_[d] = 0.f;
        float l = 0.f;
        #pragma unroll
        for (int j = 0; j < NTOK; ++j) {
            float e = __expf(sreg[j] - m);
            l += e;
            #pragma unroll
            for (int d4 = 0; d4 < 8; ++d4) {
                float4 vj = *reinterpret_cast<const float4*>(&kv_s[j*KV_STRIDE + 96 + h*HD + d4*4]);
                o_[d4*4+0] = fmaf(e, vj.x, o_[d4*4+0]);
                o_[d4*4+1] = fmaf(e, vj.y, o_[d4*4+1]);
                o_[d4*4+2] = fmaf(e, vj.z, o_[d4*4+2]);
                o_[d4*4+3] = fmaf(e, vj.w, o_[d4*4+3]);
            }
        }
        float rinv = 1.0f / l;
        #pragma unroll
        for (int d4 = 0; d4 < 8; ++d4) {
            *reinterpret_cast<float4*>(&kv_s[i*KV_STRIDE + h*HD + d4*4]) =
                make_float4(o_[d4*4+0]*rinv, o_[d4*4+1]*rinv, o_[d4*4+2]*rinv, o_[d4*4+3]*rinv);
        }
    }
    __syncthreads();   // attention outputs in kv_s cols 0..95

    // ---- proj: thread (t=lane, wv) computes c = wv*24 .. +23 ----
    {
        int t = lane;
        int c0 = wv*24;
        float acc[24];
        #pragma unroll
        for (int k = 0; k < 24; ++k) acc[k] = proj_b[c0 + k];
        for (int k4 = 0; k4 < 24; ++k4) {
            float4 ov = *reinterpret_cast<const float4*>(&kv_s[t*KV_STRIDE + k4*4]);
            #pragma unroll
            for (int kk = 0; kk < 4; ++kk) {
                float oc = (&ov.x)[kk];
                int kd = k4*4 + kk;
                #pragma unroll
                for (int c = 0; c < 24; ++c)
                    acc[c] = fmaf(oc, proj_w[(c0 + c)*DIM + kd], acc[c]);
            }
        }
        #pragma unroll
        for (int c4 = 0; c4 < 6; ++c4)
            *reinterpret_cast<float4*>(&x_s[t*XS_STRIDE + c0 + c4*4]) =
                make_float4(acc[c4*4+0], acc[c4*4+1], acc[c4*4+2], acc[c4*4+3]);
    }
    __syncthreads();

    // coalesced write-out (96-float runs per row)
    for (int idx = tid; idx < NTOK*DIM; idx += 256) {
        int t = idx / DIM, c = idx - t*DIM;
        y[xbase[t] + c] = x_s[t*XS_STRIDE + c];
    }
}

// ---------------- fused LN + residual + MLP + LN + residual (64 tokens/block) ----------------
#define TOKB 64
__global__ __launch_bounds__(256, 3)
void mlp_kernel(const float* __restrict__ x, const float* __restrict__ yin,
                const float* __restrict__ g1, const float* __restrict__ b1v,
                const float* __restrict__ fc1_w, const float* __restrict__ fc1_b,
                const float* __restrict__ fc2_w, const float* __restrict__ fc2_b,
                const float* __restrict__ g2, const float* __restrict__ b2v,
                float* __restrict__ out) {
    __shared__ float x1[TOKB * XS_STRIDE];   // 25.6 KB
    __shared__ float buf[TOKB * XS_STRIDE];  // 25.6 KB (h-tile stride 68, then out staging)
    __shared__ float psum[4*TOKB], psq[4*TOKB];
    __shared__ float mu_s[TOKB], rs_s[TOKB];

    int tid  = threadIdx.x;
    int lane = tid & 63;
    int wv   = __builtin_amdgcn_readfirstlane(tid >> 6);
    long base = (long)blockIdx.x * TOKB * DIM;

    // stage attention output (contiguous, coalesced)
    for (int idx = tid; idx < TOKB*24; idx += 256) {
        int r = idx / 24, c4 = idx - r*24;
        float4 v = *reinterpret_cast<const float4*>(yin + base + idx*4);
        *reinterpret_cast<float4*>(&x1[r*XS_STRIDE + c4*4]) = v;
    }
    __syncthreads();

    // LN1 stats (partials per (wave, token))
    {
        int t = lane, c0 = wv*24;
        float s = 0.f, sq = 0.f;
        #pragma unroll
        for (int c4 = 0; c4 < 6; ++c4) {
            float4 v = *reinterpret_cast<const float4*>(&x1[t*XS_STRIDE + c0 + c4*4]);
            s  += v.x + v.y + v.z + v.w;
            sq += v.x*v.x + v.y*v.y + v.z*v.z + v.w*v.w;
        }
        psum[wv*TOKB + t] = s; psq[wv*TOKB + t] = sq;
    }
    __syncthreads();
    if (tid < TOKB) {
        float s  = psum[tid] + psum[64+tid] + psum[128+tid] + psum[192+tid];
        float sq = psq[tid]  + psq[64+tid]  + psq[128+tid]  + psq[192+tid];
        float mu = s * (1.0f/DIM);
        float var = sq * (1.0f/DIM) - mu*mu;
        mu_s[tid] = mu;
        rs_s[tid] = rsqrtf(fmaxf(var, 0.f) + 1e-5f);
    }
    __syncthreads();
    // x1 <- x + LN1(y)   (coalesced x read)
    for (int idx = tid; idx < TOKB*24; idx += 256) {
        int r = idx / 24, c4 = idx - r*24;
        float4 xg  = *reinterpret_cast<const float4*>(x + base + idx*4);
        float4 raw = *reinterpret_cast<const float4*>(&x1[r*XS_STRIDE + c4*4]);
        float mu = mu_s[r], rs = rs_s[r];
        float4 res;
        res.x = xg.x + (raw.x - mu)*rs*g1[c4*4+0] + b1v[c4*4+0];
        res.y = xg.y + (raw.y - mu)*rs*g1[c4*4+1] + b1v[c4*4+1];
        res.z = xg.z + (raw.z - mu)*rs*g1[c4*4+2] + b1v[c4*4+2];
        res.w = xg.w + (raw.w - mu)*rs*g1[c4*4+3] + b1v[c4*4+3];
        *reinterpret_cast<float4*>(&x1[r*XS_STRIDE + c4*4]) = res;
    }
    __syncthreads();

    // fc2 accumulators held across 6 o-tiles
    float acc2[24];
    {
        int c0 = wv*24;
        #pragma unroll
        for (int k = 0; k < 24; ++k) acc2[k] = fc2_b[c0 + k];
    }

    for (int ot = 0; ot < 6; ++ot) {
        int o0 = ot*64;
        // fc1 tile: h[t][o0 + wv*16 + g], g=0..15
        {
            int t = lane, oo0 = wv*16;
            float a1[16];
            #pragma unroll
            for (int g = 0; g < 16; ++g) a1[g] = fc1_b[o0 + oo0 + g];
            for (int c4 = 0; c4 < 24; ++c4) {
                float4 xv = *reinterpret_cast<const float4*>(&x1[t*XS_STRIDE + c4*4]);
                #pragma unroll
                for (int cc = 0; cc < 4; ++cc) {
                    float xc = (&xv.x)[cc];
                    int c = c4*4 + cc;
                    #pragma unroll
                    for (int g = 0; g < 16; ++g)
                        a1[g] = fmaf(xc, fc1_w[(o0 + oo0 + g)*DIM + c], a1[g]);
                }
            }
            #pragma unroll
            for (int g4 = 0; g4 < 4; ++g4) {
                float4 hv;
                float a;
                a = a1[g4*4+0]; hv.x = 0.5f*a*(1.0f + erff(a*0.70710678118654752f));
                a = a1[g4*4+1]; hv.y = 0.5f*a*(1.0f + erff(a*0.70710678118654752f));
                a = a1[g4*4+2]; hv.z = 0.5f*a*(1.0f + erff(a*0.70710678118654752f));
                a = a1[g4*4+3]; hv.w = 0.5f*a*(1.0f + erff(a*0.70710678118654752f));
                *reinterpret_cast<float4*>(&buf[t*68 + oo0 + g4*4]) = hv;
            }
        }
        __syncthreads();
        // fc2 partial: acc2[k] += h[t][o] * w2[c0+k][o]
        {
            int t = lane, c0 = wv*24;
            for (int oo4 = 0; oo4 < 16; ++oo4) {
                float4 hv = *reinterpret_cast<const float4*>(&buf[t*68 + oo4*4]);
                #pragma unroll
                for (int kk = 0; kk < 4; ++kk) {
                    float hc = (&hv.x)[kk];
                    int o = o0 + oo4*4 + kk;
                    #pragma unroll
                    for (int k = 0; k < 24; ++k)
                        acc2[k] = fmaf(hc, fc2_w[(c0 + k)*384 + o], acc2[k]);
                }
            }
        }
        __syncthreads();
    }

    // LN2 stats from registers
    {
        int t = lane;
        float s = 0.f, sq = 0.f;
        #pragma unroll
        for (int k = 0; k < 24; ++k) { s += acc2[k]; sq += acc2[k]*acc2[k]; }
        psum[wv*TOKB + t] = s; psq[wv*TOKB + t] = sq;
    }
    __syncthreads();
    if (tid < TOKB) {
        float s  = psum[tid] + psum[64+tid] + psum[128+tid] + psum[192+tid];
        float sq = psq[tid]  + psq[64+tid]  + psq[128+tid]  + psq[192+tid];
        float mu = s * (1.0f/DIM);
        float var = sq * (1.0f/DIM) - mu*mu;
        mu_s[tid] = mu;
        rs_s[tid] = rsqrtf(fmaxf(var, 0.f) + 1e-5f);
    }
    __syncthreads();
    // out = x1 + LN2(h2), staged to buf then coalesced write
    {
        int t = lane, c0 = wv*24;
        float mu = mu_s[t], rs = rs_s[t];
        #pragma unroll
        for (int k4 = 0; k4 < 6; ++k4) {
            float4 xv = *reinterpret_cast<const float4*>(&x1[t*XS_STRIDE + c0 + k4*4]);
            float4 ov;
            ov.x = xv.x + (acc2[k4*4+0]-mu)*rs*g2[c0+k4*4+0] + b2v[c0+k4*4+0];
            ov.y = xv.y + (acc2[k4*4+1]-mu)*rs*g2[c0+k4*4+1] + b2v[c0+k4*4+1];
            ov.z = xv.z + (acc2[k4*4+2]-mu)*rs*g2[c0+k4*4+2] + b2v[c0+k4*4+2];
            ov.w = xv.w + (acc2[k4*4+3]-mu)*rs*g2[c0+k4*4+3] + b2v[c0+k4*4+3];
            *reinterpret_cast<float4*>(&buf[t*XS_STRIDE + c0 + k4*4]) = ov;
        }
    }
    __syncthreads();
    for (int idx = tid; idx < TOKB*DIM; idx += 256) {
        int r = idx / DIM, c = idx - r*DIM;
        out[base + idx] = buf[r*XS_STRIDE + c];
    }
}

extern "C" void kernel_launch(void* const* d_in, const int* in_sizes, int n_in,
                              void* d_out, int out_size, void* d_ws, size_t ws_size,
                              hipStream_t stream) {
    const float* x      = (const float*)d_in[0];
    const float* qkv_w  = (const float*)d_in[1];
    const float* q_bias = (const float*)d_in[2];
    const float* v_bias = (const float*)d_in[3];
    const float* lscale = (const float*)d_in[4];
    const float* cpb_w1 = (const float*)d_in[5];
    const float* cpb_b1 = (const float*)d_in[6];
    const float* cpb_w2 = (const float*)d_in[7];
    const float* proj_w = (const float*)d_in[8];
    const float* proj_b = (const float*)d_in[9];
    const float* n1g    = (const float*)d_in[10];
    const float* n1b    = (const float*)d_in[11];
    const float* fc1_w  = (const float*)d_in[12];
    const float* fc1_b  = (const float*)d_in[13];
    const float* fc2_w  = (const float*)d_in[14];
    const float* fc2_b  = (const float*)d_in[15];
    const float* n2g    = (const float*)d_in[16];
    const float* n2b    = (const float*)d_in[17];
    float* out = (float*)d_out;

    float* tbl  = (float*)d_ws;               // 343*3 floats
    float* rpbT = (float*)d_ws + 2048;        // 3*64*64 floats

    cpb_table_kernel<<<343, 256, 0, stream>>>(cpb_w1, cpb_b1, cpb_w2, tbl);
    rpb_kernel<<<192, 64, 0, stream>>>(tbl, rpbT);
    attn_kernel<<<2*NWIN, 256, 0, stream>>>(x, qkv_w, q_bias, v_bias, lscale,
                                            proj_w, proj_b, rpbT, out);
    mlp_kernel<<<(2*RES*RES*RES)/TOKB, 256, 0, stream>>>(x, out, n1g, n1b,
                                                         fc1_w, fc1_b, fc2_w, fc2_b,
                                                         n2g, n2b, out);
}

// Round 3
// 743.002 us; speedup vs baseline: 8.5445x; 2.1405x over previous
//
#include <hip/hip_runtime.h>
#include <math.h>

#define RES   48
#define WS    4
#define SSH   2
#define DIM   96
#define HEADS 3
#define HD    32
#define NTOK  64
#define NWAX  12
#define NWIN  (NWAX*NWAX*NWAX)   // 1728

#define XS_STRIDE 100   // dwords: 16B-quad stride 25 (odd) -> conflict-free b128
#define KV_STRIDE 196   // dwords: 16B-quad stride 49 (odd) -> conflict-free b128

typedef float f32x4 __attribute__((ext_vector_type(4)));
typedef short s16x8 __attribute__((ext_vector_type(8)));

__device__ __forceinline__ short f2bf(float f) {
    unsigned u = __builtin_bit_cast(unsigned, f);
    u = (u + 0x7FFFu + ((u >> 16) & 1u)) >> 16;
    return (short)u;
}

__device__ __forceinline__ int region(int g) {
    return (g < RES - WS) ? 0 : ((g < RES - SSH) ? 1 : 2);
}

// ---------------- CPB table: hidden(512) relu -> 3 heads, per 343 coords ----------------
__global__ void cpb_table_kernel(const float* __restrict__ w1, const float* __restrict__ b1,
                                 const float* __restrict__ w2, float* __restrict__ tbl) {
    __shared__ float hid[512];
    int ti = blockIdx.x;                 // 0..342
    int a = ti / 49, b = (ti / 7) % 7, c = ti % 7;
    float comp[3] = {(float)(a - 3), (float)(b - 3), (float)(c - 3)};
    float f[3];
    #pragma unroll
    for (int k = 0; k < 3; ++k) {
        float u = (comp[k] / 3.0f) * 8.0f;
        float s = (u > 0.f) ? 1.f : ((u < 0.f) ? -1.f : 0.f);
        f[k] = s * log2f(fabsf(u) + 1.0f) * (1.0f / 3.0f);
    }
    for (int j = threadIdx.x; j < 512; j += blockDim.x) {
        float acc = b1[j] + f[0]*w1[j*3+0] + f[1]*w1[j*3+1] + f[2]*w1[j*3+2];
        hid[j] = fmaxf(acc, 0.f);
    }
    __syncthreads();
    int tid = threadIdx.x;
    if (tid < 192) {
        int h = tid >> 6, lane = tid & 63;
        float p = 0.f;
        for (int j = lane; j < 512; j += 64) p += w2[h*512 + j] * hid[j];
        #pragma unroll
        for (int off = 32; off; off >>= 1) p += __shfl_down(p, off, 64);
        if (lane == 0) tbl[ti*3 + h] = p;
    }
}

// ---------------- rpbT[h][j][i] = 16*sigmoid(tbl[rpi(i,j)][h])  (TRANSPOSED) ----------------
__global__ void rpb_kernel(const float* __restrict__ tbl, float* __restrict__ rpbT) {
    int bi = blockIdx.x;                 // h*64 + i
    int h = bi >> 6, i = bi & 63;
    int j = threadIdx.x;                 // 0..63
    int hi = i >> 4, wi = (i >> 2) & 3, di = i & 3;
    int hj = j >> 4, wj = (j >> 2) & 3, dj = j & 3;
    int idx = (hi - hj + 3)*49 + (wi - wj + 3)*7 + (di - dj + 3);
    float v = tbl[idx*3 + h];
    rpbT[(h*64 + j)*64 + i] = 16.0f / (1.0f + expf(-v));
}

// ---------------- pack MLP weights to bf16 in MFMA fragment order ----------------
// fc1 (o in [0,384), c in [0,96)):  tile=(o>>4)*3+(c>>5), lane=((c>>3)&3)*16+(o&15), elem=c&7
// fc2 (co in [0,96), oo in [0,384)): tile=(co>>4)*12+(oo>>5), lane=((oo>>3)&3)*16+(co&15), elem=oo&7
__global__ void pack_mlp_w(const float* __restrict__ fc1_w, const float* __restrict__ fc2_w,
                           short* __restrict__ w1p, short* __restrict__ w2p) {
    int i = blockIdx.x*256 + threadIdx.x;
    if (i >= 36864) return;
    {
        int o = i / 96, c = i - o*96;
        int tile = (o >> 4)*3 + (c >> 5);
        int lane = ((c >> 3) & 3)*16 + (o & 15);
        w1p[tile*512 + lane*8 + (c & 7)] = f2bf(fc1_w[i]);
    }
    {
        int co = i / 384, oo = i - co*384;
        int tile = (co >> 4)*12 + (oo >> 5);
        int lane = ((oo >> 3) & 3)*16 + (co & 15);
        w2p[tile*512 + lane*8 + (oo & 7)] = f2bf(fc2_w[i]);
    }
}

// ---------------- window attention (unchanged from round 2) ----------------
__global__ __launch_bounds__(256, 2)
void attn_kernel(const float* __restrict__ x, const float* __restrict__ qkv_w,
                 const float* __restrict__ q_bias, const float* __restrict__ v_bias,
                 const float* __restrict__ logit_scale,
                 const float* __restrict__ proj_w, const float* __restrict__ proj_b,
                 const float* __restrict__ rpbT, float* __restrict__ y) {
    __shared__ float x_s[NTOK * XS_STRIDE];
    __shared__ float kv_s[NTOK * KV_STRIDE];
    __shared__ float knorm_s[192];
    __shared__ int xbase[NTOK];
    __shared__ int cnt[NTOK];

    int tid  = threadIdx.x;
    int lane = tid & 63;
    int wv   = __builtin_amdgcn_readfirstlane(tid >> 6);

    int wid = blockIdx.x;
    int b   = wid / NWIN;
    int rem = wid - b*NWIN;
    int wh = rem / (NWAX*NWAX);
    int ww = (rem / NWAX) % NWAX;
    int wd = rem % NWAX;

    if (tid < NTOK) {
        int t = tid;
        int lh = t >> 4, lw = (t >> 2) & 3, ld = t & 3;
        int gh = wh*WS + lh, gw = ww*WS + lw, gd = wd*WS + ld;
        int sh = (gh + SSH) % RES, sw = (gw + SSH) % RES, sd = (gd + SSH) % RES;
        xbase[t] = (((b*RES + sh)*RES + sw)*RES + sd)*DIM;
        cnt[t]   = region(gh)*9 + region(gw)*3 + region(gd);
    }
    __syncthreads();

    for (int idx = tid; idx < NTOK*24; idx += 256) {
        int r = idx / 24, c4 = idx - r*24;
        float4 v = *reinterpret_cast<const float4*>(x + xbase[r] + c4*4);
        *reinterpret_cast<float4*>(&x_s[r*XS_STRIDE + c4*4]) = v;
    }
    __syncthreads();

    {
        int t = lane;
        for (int og = 0; og < 6; ++og) {
            int o0 = wv*48 + og*8;
            float acc[8];
            #pragma unroll
            for (int r = 0; r < 8; ++r)
                acc[r] = (o0 + r < 96) ? 0.0f : v_bias[o0 + r - 96];
            for (int c4 = 0; c4 < 24; ++c4) {
                float4 xv = *reinterpret_cast<const float4*>(&x_s[t*XS_STRIDE + c4*4]);
                #pragma unroll
                for (int cc = 0; cc < 4; ++cc) {
                    float xc = (&xv.x)[cc];
                    int c = c4*4 + cc;
                    #pragma unroll
                    for (int r = 0; r < 8; ++r)
                        acc[r] = fmaf(xc, qkv_w[(96 + o0 + r)*DIM + c], acc[r]);
                }
            }
            *reinterpret_cast<float4*>(&kv_s[t*KV_STRIDE + o0])     = make_float4(acc[0],acc[1],acc[2],acc[3]);
            *reinterpret_cast<float4*>(&kv_s[t*KV_STRIDE + o0 + 4]) = make_float4(acc[4],acc[5],acc[6],acc[7]);
        }
    }

    float q[HD];
    int h = wv;
    int i = lane;
    if (tid < 192) {
        #pragma unroll
        for (int d = 0; d < HD; ++d) q[d] = q_bias[h*HD + d];
        for (int c4 = 0; c4 < 24; ++c4) {
            float4 xv = *reinterpret_cast<const float4*>(&x_s[i*XS_STRIDE + c4*4]);
            #pragma unroll
            for (int cc = 0; cc < 4; ++cc) {
                float xc = (&xv.x)[cc];
                int c = c4*4 + cc;
                #pragma unroll
                for (int d = 0; d < HD; ++d)
                    q[d] = fmaf(xc, qkv_w[(h*HD + d)*DIM + c], q[d]);
            }
        }
        float qn = 0.f;
        #pragma unroll
        for (int d = 0; d < HD; ++d) qn += q[d]*q[d];
        float sc = expf(fminf(logit_scale[h], 4.605170185988092f));
        float qr = sc / fmaxf(sqrtf(qn), 1e-12f);
        #pragma unroll
        for (int d = 0; d < HD; ++d) q[d] *= qr;
    }
    __syncthreads();

    if (tid < 192) {
        float kn = 0.f;
        #pragma unroll
        for (int d4 = 0; d4 < 8; ++d4) {
            float4 kv = *reinterpret_cast<const float4*>(&kv_s[i*KV_STRIDE + h*HD + d4*4]);
            kn += kv.x*kv.x + kv.y*kv.y + kv.z*kv.z + kv.w*kv.w;
        }
        knorm_s[h*64 + i] = 1.0f / fmaxf(sqrtf(kn), 1e-12f);
        __threadfence_block();

        int ci = cnt[i];
        float sreg[NTOK];
        float m = -1e30f;
        #pragma unroll
        for (int j = 0; j < NTOK; ++j) {
            float s = 0.f;
            #pragma unroll
            for (int d4 = 0; d4 < 8; ++d4) {
                float4 kj = *reinterpret_cast<const float4*>(&kv_s[j*KV_STRIDE + h*HD + d4*4]);
                s = fmaf(q[d4*4+0], kj.x, s);
                s = fmaf(q[d4*4+1], kj.y, s);
                s = fmaf(q[d4*4+2], kj.z, s);
                s = fmaf(q[d4*4+3], kj.w, s);
            }
            s = s * knorm_s[h*64 + j] + rpbT[(h*64 + j)*64 + i];
            if (ci != cnt[j]) s -= 100.0f;
            sreg[j] = s;
            m = fmaxf(m, s);
        }

        float o_[HD];
        #pragma unroll
        for (int d = 0; d < HD; ++d) o_[d] = 0.f;
        float l = 0.f;
        #pragma unroll
        for (int j = 0; j < NTOK; ++j) {
            float e = __expf(sreg[j] - m);
            l += e;
            #pragma unroll
            for (int d4 = 0; d4 < 8; ++d4) {
                float4 vj = *reinterpret_cast<const float4*>(&kv_s[j*KV_STRIDE + 96 + h*HD + d4*4]);
                o_[d4*4+0] = fmaf(e, vj.x, o_[d4*4+0]);
                o_[d4*4+1] = fmaf(e, vj.y, o_[d4*4+1]);
                o_[d4*4+2] = fmaf(e, vj.z, o_[d4*4+2]);
                o_[d4*4+3] = fmaf(e, vj.w, o_[d4*4+3]);
            }
        }
        float rinv = 1.0f / l;
        #pragma unroll
        for (int d4 = 0; d4 < 8; ++d4) {
            *reinterpret_cast<float4*>(&kv_s[i*KV_STRIDE + h*HD + d4*4]) =
                make_float4(o_[d4*4+0]*rinv, o_[d4*4+1]*rinv, o_[d4*4+2]*rinv, o_[d4*4+3]*rinv);
        }
    }
    __syncthreads();

    {
        int t = lane;
        int c0 = wv*24;
        float acc[24];
        #pragma unroll
        for (int k = 0; k < 24; ++k) acc[k] = proj_b[c0 + k];
        for (int k4 = 0; k4 < 24; ++k4) {
            float4 ov = *reinterpret_cast<const float4*>(&kv_s[t*KV_STRIDE + k4*4]);
            #pragma unroll
            for (int kk = 0; kk < 4; ++kk) {
                float oc = (&ov.x)[kk];
                int kd = k4*4 + kk;
                #pragma unroll
                for (int c = 0; c < 24; ++c)
                    acc[c] = fmaf(oc, proj_w[(c0 + c)*DIM + kd], acc[c]);
            }
        }
        #pragma unroll
        for (int c4 = 0; c4 < 6; ++c4)
            *reinterpret_cast<float4*>(&x_s[t*XS_STRIDE + c0 + c4*4]) =
                make_float4(acc[c4*4+0], acc[c4*4+1], acc[c4*4+2], acc[c4*4+3]);
    }
    __syncthreads();

    for (int idx = tid; idx < NTOK*DIM; idx += 256) {
        int t = idx / DIM, c = idx - t*DIM;
        y[xbase[t] + c] = x_s[t*XS_STRIDE + c];
    }
}

// ---------------- MFMA MLP: LN1 + fc1(gelu) + fc2 + LN2, 64 tokens/block ----------------
#define XB_STR 104   // bf16 stride for x1 (2-way max on b128 reads)
#define H_STR  392   // bf16 stride for h  (rows 16B-aligned, 2-way max)

__global__ __launch_bounds__(256, 2)
void mlp_mfma_kernel(const float* __restrict__ x, const float* __restrict__ yin,
                     const float* __restrict__ g1, const float* __restrict__ b1v,
                     const short* __restrict__ w1p, const float* __restrict__ fc1_b,
                     const short* __restrict__ w2p, const float* __restrict__ fc2_b,
                     const float* __restrict__ g2, const float* __restrict__ b2v,
                     float* __restrict__ out) {
    __shared__ short x1b[64 * XB_STR];   // 13.3 KB
    __shared__ short hb[64 * H_STR];     // 50.2 KB

    int tid = threadIdx.x;
    int l   = tid & 63;
    int w   = __builtin_amdgcn_readfirstlane(tid >> 6);
    int lc  = l & 15;    // MFMA col lane
    int lg  = l >> 4;    // MFMA row group
    long base = (long)blockIdx.x * 64 * DIM;

    // ---- load yin/x in D-layout, LN1 via shuffles, keep x1 in regs + bf16 LDS ----
    float yv[6][4], xv[6][4], x1v[6][4];
    #pragma unroll
    for (int r = 0; r < 4; ++r) {
        int t = w*16 + lg*4 + r;
        #pragma unroll
        for (int n = 0; n < 6; ++n) {
            int c = n*16 + lc;
            yv[n][r] = yin[base + t*DIM + c];
            xv[n][r] = x[base + t*DIM + c];
        }
    }
    #pragma unroll
    for (int r = 0; r < 4; ++r) {
        float s = 0.f, sq = 0.f;
        #pragma unroll
        for (int n = 0; n < 6; ++n) { float v = yv[n][r]; s += v; sq += v*v; }
        #pragma unroll
        for (int m = 1; m < 16; m <<= 1) { s += __shfl_xor(s, m, 64); sq += __shfl_xor(sq, m, 64); }
        float mu  = s * (1.0f/DIM);
        float var = sq * (1.0f/DIM) - mu*mu;
        float rs  = rsqrtf(fmaxf(var, 0.f) + 1e-5f);
        int t = w*16 + lg*4 + r;
        #pragma unroll
        for (int n = 0; n < 6; ++n) {
            int c = n*16 + lc;
            float v = xv[n][r] + (yv[n][r] - mu)*rs*g1[c] + b1v[c];
            x1v[n][r] = v;
            x1b[t*XB_STR + c] = f2bf(v);
        }
    }
    __syncthreads();

    // ---- fc1: wave w owns output cols [w*96, w*96+96), all 4 M-tiles ----
    f32x4 acc1[4][6];
    #pragma unroll
    for (int n = 0; n < 6; ++n) {
        float b = fc1_b[w*96 + n*16 + lc];
        #pragma unroll
        for (int m = 0; m < 4; ++m) acc1[m][n] = f32x4{b, b, b, b};
    }
    #pragma unroll
    for (int ks = 0; ks < 3; ++ks) {
        s16x8 af[4];
        #pragma unroll
        for (int m = 0; m < 4; ++m)
            af[m] = *reinterpret_cast<const s16x8*>(&x1b[(m*16 + lc)*XB_STR + ks*32 + lg*8]);
        #pragma unroll
        for (int n = 0; n < 6; ++n) {
            s16x8 bf = *reinterpret_cast<const s16x8*>(&w1p[((w*6 + n)*3 + ks)*512 + l*8]);
            #pragma unroll
            for (int m = 0; m < 4; ++m)
                acc1[m][n] = __builtin_amdgcn_mfma_f32_16x16x32_bf16(af[m], bf, acc1[m][n], 0, 0, 0);
        }
    }

    // ---- gelu -> bf16 -> hb ----
    #pragma unroll
    for (int m = 0; m < 4; ++m) {
        #pragma unroll
        for (int n = 0; n < 6; ++n) {
            int col = w*96 + n*16 + lc;
            #pragma unroll
            for (int r = 0; r < 4; ++r) {
                int row = m*16 + lg*4 + r;
                float a = acc1[m][n][r];
                float gel = 0.5f*a*(1.0f + erff(a*0.70710678118654752f));
                hb[row*H_STR + col] = f2bf(gel);
            }
        }
    }
    __syncthreads();

    // ---- fc2: wave w owns M-tile w, all 6 N-tiles, K=384 ----
    f32x4 acc2[6];
    #pragma unroll
    for (int n = 0; n < 6; ++n) {
        float b = fc2_b[n*16 + lc];
        acc2[n] = f32x4{b, b, b, b};
    }
    #pragma unroll
    for (int ks = 0; ks < 12; ++ks) {
        s16x8 af = *reinterpret_cast<const s16x8*>(&hb[(w*16 + lc)*H_STR + ks*32 + lg*8]);
        #pragma unroll
        for (int n = 0; n < 6; ++n) {
            s16x8 bf = *reinterpret_cast<const s16x8*>(&w2p[(n*12 + ks)*512 + l*8]);
            acc2[n] = __builtin_amdgcn_mfma_f32_16x16x32_bf16(af, bf, acc2[n], 0, 0, 0);
        }
    }

    // ---- LN2 via shuffles + residual + write ----
    #pragma unroll
    for (int r = 0; r < 4; ++r) {
        float s = 0.f, sq = 0.f;
        #pragma unroll
        for (int n = 0; n < 6; ++n) { float v = acc2[n][r]; s += v; sq += v*v; }
        #pragma unroll
        for (int m = 1; m < 16; m <<= 1) { s += __shfl_xor(s, m, 64); sq += __shfl_xor(sq, m, 64); }
        float mu  = s * (1.0f/DIM);
        float var = sq * (1.0f/DIM) - mu*mu;
        float rs  = rsqrtf(fmaxf(var, 0.f) + 1e-5f);
        int t = w*16 + lg*4 + r;
        #pragma unroll
        for (int n = 0; n < 6; ++n) {
            int c = n*16 + lc;
            out[base + t*DIM + c] = x1v[n][r] + (acc2[n][r] - mu)*rs*g2[c] + b2v[c];
        }
    }
}

extern "C" void kernel_launch(void* const* d_in, const int* in_sizes, int n_in,
                              void* d_out, int out_size, void* d_ws, size_t ws_size,
                              hipStream_t stream) {
    const float* x      = (const float*)d_in[0];
    const float* qkv_w  = (const float*)d_in[1];
    const float* q_bias = (const float*)d_in[2];
    const float* v_bias = (const float*)d_in[3];
    const float* lscale = (const float*)d_in[4];
    const float* cpb_w1 = (const float*)d_in[5];
    const float* cpb_b1 = (const float*)d_in[6];
    const float* cpb_w2 = (const float*)d_in[7];
    const float* proj_w = (const float*)d_in[8];
    const float* proj_b = (const float*)d_in[9];
    const float* n1g    = (const float*)d_in[10];
    const float* n1b    = (const float*)d_in[11];
    const float* fc1_w  = (const float*)d_in[12];
    const float* fc1_b  = (const float*)d_in[13];
    const float* fc2_w  = (const float*)d_in[14];
    const float* fc2_b  = (const float*)d_in[15];
    const float* n2g    = (const float*)d_in[16];
    const float* n2b    = (const float*)d_in[17];
    float* out = (float*)d_out;

    float* tbl  = (float*)d_ws;               // 343*3 floats
    float* rpbT = (float*)d_ws + 2048;        // 3*64*64 floats (ends at 14336)
    short* w1p  = (short*)((float*)d_ws + 16384);   // 36864 bf16
    short* w2p  = w1p + 36864;                      // 36864 bf16

    cpb_table_kernel<<<343, 256, 0, stream>>>(cpb_w1, cpb_b1, cpb_w2, tbl);
    rpb_kernel<<<192, 64, 0, stream>>>(tbl, rpbT);
    pack_mlp_w<<<144, 256, 0, stream>>>(fc1_w, fc2_w, w1p, w2p);
    attn_kernel<<<2*NWIN, 256, 0, stream>>>(x, qkv_w, q_bias, v_bias, lscale,
                                            proj_w, proj_b, rpbT, out);
    mlp_mfma_kernel<<<(2*RES*RES*RES)/64, 256, 0, stream>>>(x, out, n1g, n1b,
                                                            w1p, fc1_b, w2p, fc2_b,
                                                            n2g, n2b, out);
}

// Round 4
// 246.546 us; speedup vs baseline: 25.7500x; 3.0136x over previous
//
#include <hip/hip_runtime.h>
#include <math.h>

#define RES   48
#define WS    4
#define SSH   2
#define DIM   96
#define HEADS 3
#define HD    32
#define NTOK  64
#define NWAX  12
#define NWIN  (NWAX*NWAX*NWAX)   // 1728

typedef float f32x4 __attribute__((ext_vector_type(4)));
typedef short s16x8 __attribute__((ext_vector_type(8)));

__device__ __forceinline__ short f2bf(float f) {
    unsigned u = __builtin_bit_cast(unsigned, f);
    u = (u + 0x7FFFu + ((u >> 16) & 1u)) >> 16;
    return (short)u;
}
__device__ __forceinline__ float bf2f(short s) {
    unsigned u = ((unsigned)(unsigned short)s) << 16;
    return __builtin_bit_cast(float, u);
}

__device__ __forceinline__ int region(int g) {
    return (g < RES - WS) ? 0 : ((g < RES - SSH) ? 1 : 2);
}

// ---------------- CPB table ----------------
__global__ void cpb_table_kernel(const float* __restrict__ w1, const float* __restrict__ b1,
                                 const float* __restrict__ w2, float* __restrict__ tbl) {
    __shared__ float hid[512];
    int ti = blockIdx.x;
    int a = ti / 49, b = (ti / 7) % 7, c = ti % 7;
    float comp[3] = {(float)(a - 3), (float)(b - 3), (float)(c - 3)};
    float f[3];
    #pragma unroll
    for (int k = 0; k < 3; ++k) {
        float u = (comp[k] / 3.0f) * 8.0f;
        float s = (u > 0.f) ? 1.f : ((u < 0.f) ? -1.f : 0.f);
        f[k] = s * log2f(fabsf(u) + 1.0f) * (1.0f / 3.0f);
    }
    for (int j = threadIdx.x; j < 512; j += blockDim.x) {
        float acc = b1[j] + f[0]*w1[j*3+0] + f[1]*w1[j*3+1] + f[2]*w1[j*3+2];
        hid[j] = fmaxf(acc, 0.f);
    }
    __syncthreads();
    int tid = threadIdx.x;
    if (tid < 192) {
        int h = tid >> 6, lane = tid & 63;
        float p = 0.f;
        for (int j = lane; j < 512; j += 64) p += w2[h*512 + j] * hid[j];
        #pragma unroll
        for (int off = 32; off; off >>= 1) p += __shfl_down(p, off, 64);
        if (lane == 0) tbl[ti*3 + h] = p;
    }
}

// ---------------- rpb[h][i][j] = 16*sigmoid(tbl[rpi(i,j)][h]) ----------------
__global__ void rpb_kernel(const float* __restrict__ tbl, float* __restrict__ rpb) {
    int bi = blockIdx.x;                 // h*64 + i
    int h = bi >> 6, i = bi & 63;
    int j = threadIdx.x;
    int hi = i >> 4, wi = (i >> 2) & 3, di = i & 3;
    int hj = j >> 4, wj = (j >> 2) & 3, dj = j & 3;
    int idx = (hi - hj + 3)*49 + (wi - wj + 3)*7 + (di - dj + 3);
    float v = tbl[idx*3 + h];
    rpb[(h*64 + i)*64 + j] = 16.0f / (1.0f + expf(-v));
}

// ---------------- pack MLP weights (B-fragment order) ----------------
__global__ void pack_mlp_w(const float* __restrict__ fc1_w, const float* __restrict__ fc2_w,
                           short* __restrict__ w1p, short* __restrict__ w2p) {
    int i = blockIdx.x*256 + threadIdx.x;
    if (i >= 36864) return;
    {
        int o = i / 96, c = i - o*96;
        int tile = (o >> 4)*3 + (c >> 5);
        int lane = ((c >> 3) & 3)*16 + (o & 15);
        w1p[tile*512 + lane*8 + (c & 7)] = f2bf(fc1_w[i]);
    }
    {
        int co = i / 384, oo = i - co*384;
        int tile = (co >> 4)*12 + (oo >> 5);
        int lane = ((oo >> 3) & 3)*16 + (co & 15);
        w2p[tile*512 + lane*8 + (oo & 7)] = f2bf(fc2_w[i]);
    }
}

// ---------------- pack attention weights ----------------
__global__ void pack_attn_w(const float* __restrict__ qkv_w, const float* __restrict__ proj_w,
                            short* __restrict__ qkvp, short* __restrict__ projp) {
    int i = blockIdx.x*256 + threadIdx.x;
    if (i < 288*96) {
        int o = i / 96, c = i - o*96;
        int tile = (o >> 4)*3 + (c >> 5);
        int lane = ((c >> 3) & 3)*16 + (o & 15);
        qkvp[tile*512 + lane*8 + (c & 7)] = f2bf(qkv_w[i]);
    }
    if (i < 96*96) {
        int co = i / 96, k = i - co*96;
        int tile = (co >> 4)*3 + (k >> 5);
        int lane = ((k >> 3) & 3)*16 + (co & 15);
        projp[tile*512 + lane*8 + (k & 7)] = f2bf(proj_w[i]);
    }
}

// ---------------- MFMA window attention ----------------
#define TSTR 104   // bf16 stride for token-major tiles (x_s/q_s/k_s/ao_s)
#define VSTR 72    // vT[dim][token]
#define PSTR 72    // p_s[token][j]

__global__ __launch_bounds__(256, 2)
void attn_mfma_kernel(const float* __restrict__ x, const short* __restrict__ qkvp,
                      const float* __restrict__ q_bias, const float* __restrict__ v_bias,
                      const float* __restrict__ logit_scale,
                      const short* __restrict__ projp, const float* __restrict__ proj_b,
                      const float* __restrict__ rpb, float* __restrict__ y) {
    __shared__ short x_s[NTOK*TSTR];   // later aliased by p_s (64*72 < 64*104)
    __shared__ short q_s[NTOK*TSTR];   // later aliased by ao_s
    __shared__ short k_s[NTOK*TSTR];
    __shared__ short vT[96*VSTR];
    __shared__ float knorm[192];
    __shared__ int xbase[NTOK];
    __shared__ int cnt_s[NTOK];

    short* p_s  = x_s;
    short* ao_s = q_s;

    int tid = threadIdx.x;
    int l   = tid & 63;
    int w   = __builtin_amdgcn_readfirstlane(tid >> 6);
    int lc  = l & 15;
    int lg  = l >> 4;

    int wid = blockIdx.x;
    int b   = wid / NWIN;
    int rem = wid - b*NWIN;
    int wh = rem / (NWAX*NWAX);
    int ww = (rem / NWAX) % NWAX;
    int wd = rem % NWAX;

    if (tid < NTOK) {
        int t = tid;
        int lh = t >> 4, lw = (t >> 2) & 3, ld = t & 3;
        int gh = wh*WS + lh, gw = ww*WS + lw, gd = wd*WS + ld;
        int sh = (gh + SSH) % RES, sw = (gw + SSH) % RES, sd = (gd + SSH) % RES;
        xbase[t] = (((b*RES + sh)*RES + sw)*RES + sd)*DIM;
        cnt_s[t] = region(gh)*9 + region(gw)*3 + region(gd);
    }
    __syncthreads();   // S1

    // stage x -> bf16 (8 floats per step)
    for (int idx = tid; idx < NTOK*12; idx += 256) {
        int r = idx / 12, g = idx - r*12;
        const float* src = x + xbase[r] + g*8;
        float4 a = *reinterpret_cast<const float4*>(src);
        float4 c = *reinterpret_cast<const float4*>(src + 4);
        s16x8 v;
        v[0]=f2bf(a.x); v[1]=f2bf(a.y); v[2]=f2bf(a.z); v[3]=f2bf(a.w);
        v[4]=f2bf(c.x); v[5]=f2bf(c.y); v[6]=f2bf(c.z); v[7]=f2bf(c.w);
        *reinterpret_cast<s16x8*>(&x_s[r*TSTR + g*8]) = v;
    }
    __syncthreads();   // S2

    // ---- QKV GEMM: 18 N-tiles round-robin over waves ----
    {
        s16x8 af[3][4];
        #pragma unroll
        for (int ks = 0; ks < 3; ++ks)
            #pragma unroll
            for (int m = 0; m < 4; ++m)
                af[ks][m] = *reinterpret_cast<const s16x8*>(&x_s[(m*16+lc)*TSTR + ks*32 + lg*8]);

        for (int nt = w; nt < 18; nt += 4) {
            int col = nt*16 + lc;
            float bias = 0.f;
            if (nt < 6) bias = q_bias[col];
            else if (nt >= 12) bias = v_bias[col - 192];
            f32x4 C[4];
            #pragma unroll
            for (int m = 0; m < 4; ++m) C[m] = f32x4{bias, bias, bias, bias};
            #pragma unroll
            for (int ks = 0; ks < 3; ++ks) {
                s16x8 bf = *reinterpret_cast<const s16x8*>(&qkvp[(nt*3+ks)*512 + l*8]);
                #pragma unroll
                for (int m = 0; m < 4; ++m)
                    C[m] = __builtin_amdgcn_mfma_f32_16x16x32_bf16(af[ks][m], bf, C[m], 0, 0, 0);
            }
            if (nt < 6) {
                #pragma unroll
                for (int m = 0; m < 4; ++m)
                    #pragma unroll
                    for (int r = 0; r < 4; ++r)
                        q_s[(m*16+lg*4+r)*TSTR + col] = f2bf(C[m][r]);
            } else if (nt < 12) {
                #pragma unroll
                for (int m = 0; m < 4; ++m)
                    #pragma unroll
                    for (int r = 0; r < 4; ++r)
                        k_s[(m*16+lg*4+r)*TSTR + col - 96] = f2bf(C[m][r]);
            } else {
                #pragma unroll
                for (int m = 0; m < 4; ++m)
                    #pragma unroll
                    for (int r = 0; r < 4; ++r)
                        vT[(col-192)*VSTR + m*16+lg*4+r] = f2bf(C[m][r]);
            }
        }
    }
    __syncthreads();   // S3

    // ---- norms: knorm table; q normalized+scaled in place ----
    if (tid < 192) {
        int h = tid >> 6, i = tid & 63;
        float n = 0.f;
        #pragma unroll
        for (int c = 0; c < 4; ++c) {
            s16x8 v = *reinterpret_cast<const s16x8*>(&k_s[i*TSTR + h*32 + c*8]);
            #pragma unroll
            for (int e = 0; e < 8; ++e) { float f = bf2f(v[e]); n += f*f; }
        }
        knorm[h*64 + i] = 1.0f / fmaxf(sqrtf(n), 1e-12f);

        s16x8 qv[4];
        float qn = 0.f;
        #pragma unroll
        for (int c = 0; c < 4; ++c) {
            qv[c] = *reinterpret_cast<const s16x8*>(&q_s[i*TSTR + h*32 + c*8]);
            #pragma unroll
            for (int e = 0; e < 8; ++e) { float f = bf2f(qv[c][e]); qn += f*f; }
        }
        float sc = __expf(fminf(logit_scale[h], 4.605170185988092f));
        float qr = sc / fmaxf(sqrtf(qn), 1e-12f);
        #pragma unroll
        for (int c = 0; c < 4; ++c) {
            s16x8 o;
            #pragma unroll
            for (int e = 0; e < 8; ++e) o[e] = f2bf(bf2f(qv[c][e]) * qr);
            *reinterpret_cast<s16x8*>(&q_s[i*TSTR + h*32 + c*8]) = o;
        }
    }
    __syncthreads();   // S4 — last barrier; waves free-run below

    // ---- QK^T: wave w owns q-rows w*16..w*16+15, all heads ----
    f32x4 sc_[3][4];
    {
        s16x8 aq[3];
        #pragma unroll
        for (int h = 0; h < 3; ++h)
            aq[h] = *reinterpret_cast<const s16x8*>(&q_s[(w*16+lc)*TSTR + h*32 + lg*8]);
        #pragma unroll
        for (int h = 0; h < 3; ++h)
            #pragma unroll
            for (int nt = 0; nt < 4; ++nt) {
                s16x8 bk = *reinterpret_cast<const s16x8*>(&k_s[(nt*16+lc)*TSTR + h*32 + lg*8]);
                sc_[h][nt] = __builtin_amdgcn_mfma_f32_16x16x32_bf16(aq[h], bk, f32x4{0.f,0.f,0.f,0.f}, 0, 0, 0);
            }
    }

    int ci[4];
    #pragma unroll
    for (int r = 0; r < 4; ++r) ci[r] = cnt_s[w*16 + lg*4 + r];
    int cjv[4];
    #pragma unroll
    for (int nt = 0; nt < 4; ++nt) cjv[nt] = cnt_s[nt*16 + lc];

    // ---- per head: softmax -> P -> PV -> staged attn-out ----
    #pragma unroll
    for (int h = 0; h < 3; ++h) {
        #pragma unroll
        for (int nt = 0; nt < 4; ++nt) {
            float kn = knorm[h*64 + nt*16 + lc];
            int cj = cjv[nt];
            #pragma unroll
            for (int r = 0; r < 4; ++r) {
                int row = w*16 + lg*4 + r;
                float s = sc_[h][nt][r]*kn + rpb[(h*64 + row)*64 + nt*16 + lc];
                if (ci[r] != cj) s -= 100.0f;
                sc_[h][nt][r] = s;
            }
        }
        float linv[4];
        #pragma unroll
        for (int r = 0; r < 4; ++r) {
            float mm = fmaxf(fmaxf(sc_[h][0][r], sc_[h][1][r]), fmaxf(sc_[h][2][r], sc_[h][3][r]));
            #pragma unroll
            for (int msk = 1; msk < 16; msk <<= 1) mm = fmaxf(mm, __shfl_xor(mm, msk, 64));
            float ll = 0.f;
            #pragma unroll
            for (int nt = 0; nt < 4; ++nt) {
                float ee = __expf(sc_[h][nt][r] - mm);
                sc_[h][nt][r] = ee;
                ll += ee;
            }
            #pragma unroll
            for (int msk = 1; msk < 16; msk <<= 1) ll += __shfl_xor(ll, msk, 64);
            linv[r] = 1.0f / ll;
        }
        #pragma unroll
        for (int nt = 0; nt < 4; ++nt)
            #pragma unroll
            for (int r = 0; r < 4; ++r)
                p_s[(w*16+lg*4+r)*PSTR + nt*16 + lc] = f2bf(sc_[h][nt][r]);

        // PV (reads only this wave's p rows -> intra-wave dep, no barrier)
        f32x4 o0 = {0.f,0.f,0.f,0.f}, o1 = {0.f,0.f,0.f,0.f};
        #pragma unroll
        for (int ks = 0; ks < 2; ++ks) {
            s16x8 ap = *reinterpret_cast<const s16x8*>(&p_s[(w*16+lc)*PSTR + ks*32 + lg*8]);
            s16x8 b0 = *reinterpret_cast<const s16x8*>(&vT[(h*32 + lc)*VSTR + ks*32 + lg*8]);
            s16x8 b1 = *reinterpret_cast<const s16x8*>(&vT[(h*32 + 16 + lc)*VSTR + ks*32 + lg*8]);
            o0 = __builtin_amdgcn_mfma_f32_16x16x32_bf16(ap, b0, o0, 0, 0, 0);
            o1 = __builtin_amdgcn_mfma_f32_16x16x32_bf16(ap, b1, o1, 0, 0, 0);
        }
        #pragma unroll
        for (int r = 0; r < 4; ++r) {
            ao_s[(w*16+lg*4+r)*TSTR + h*32 + lc]      = f2bf(o0[r]*linv[r]);
            ao_s[(w*16+lg*4+r)*TSTR + h*32 + 16 + lc] = f2bf(o1[r]*linv[r]);
        }
    }

    // ---- proj (own-wave rows only) ----
    {
        s16x8 aa[3];
        #pragma unroll
        for (int ks = 0; ks < 3; ++ks)
            aa[ks] = *reinterpret_cast<const s16x8*>(&ao_s[(w*16+lc)*TSTR + ks*32 + lg*8]);
        int xb[4];
        #pragma unroll
        for (int r = 0; r < 4; ++r) xb[r] = xbase[w*16 + lg*4 + r];
        #pragma unroll
        for (int nt = 0; nt < 6; ++nt) {
            float bias = proj_b[nt*16 + lc];
            f32x4 C = f32x4{bias, bias, bias, bias};
            #pragma unroll
            for (int ks = 0; ks < 3; ++ks) {
                s16x8 bf = *reinterpret_cast<const s16x8*>(&projp[(nt*3+ks)*512 + l*8]);
                C = __builtin_amdgcn_mfma_f32_16x16x32_bf16(aa[ks], bf, C, 0, 0, 0);
            }
            #pragma unroll
            for (int r = 0; r < 4; ++r)
                y[xb[r] + nt*16 + lc] = C[r];
        }
    }
}

// ---------------- MFMA MLP (unchanged from round 3) ----------------
#define XB_STR 104
#define H_STR  392

__global__ __launch_bounds__(256, 2)
void mlp_mfma_kernel(const float* __restrict__ x, const float* __restrict__ yin,
                     const float* __restrict__ g1, const float* __restrict__ b1v,
                     const short* __restrict__ w1p, const float* __restrict__ fc1_b,
                     const short* __restrict__ w2p, const float* __restrict__ fc2_b,
                     const float* __restrict__ g2, const float* __restrict__ b2v,
                     float* __restrict__ out) {
    __shared__ short x1b[64 * XB_STR];
    __shared__ short hb[64 * H_STR];

    int tid = threadIdx.x;
    int l   = tid & 63;
    int w   = __builtin_amdgcn_readfirstlane(tid >> 6);
    int lc  = l & 15;
    int lg  = l >> 4;
    long base = (long)blockIdx.x * 64 * DIM;

    float yv[6][4], xv[6][4], x1v[6][4];
    #pragma unroll
    for (int r = 0; r < 4; ++r) {
        int t = w*16 + lg*4 + r;
        #pragma unroll
        for (int n = 0; n < 6; ++n) {
            int c = n*16 + lc;
            yv[n][r] = yin[base + t*DIM + c];
            xv[n][r] = x[base + t*DIM + c];
        }
    }
    #pragma unroll
    for (int r = 0; r < 4; ++r) {
        float s = 0.f, sq = 0.f;
        #pragma unroll
        for (int n = 0; n < 6; ++n) { float v = yv[n][r]; s += v; sq += v*v; }
        #pragma unroll
        for (int m = 1; m < 16; m <<= 1) { s += __shfl_xor(s, m, 64); sq += __shfl_xor(sq, m, 64); }
        float mu  = s * (1.0f/DIM);
        float var = sq * (1.0f/DIM) - mu*mu;
        float rs  = rsqrtf(fmaxf(var, 0.f) + 1e-5f);
        int t = w*16 + lg*4 + r;
        #pragma unroll
        for (int n = 0; n < 6; ++n) {
            int c = n*16 + lc;
            float v = xv[n][r] + (yv[n][r] - mu)*rs*g1[c] + b1v[c];
            x1v[n][r] = v;
            x1b[t*XB_STR + c] = f2bf(v);
        }
    }
    __syncthreads();

    f32x4 acc1[4][6];
    #pragma unroll
    for (int n = 0; n < 6; ++n) {
        float b = fc1_b[w*96 + n*16 + lc];
        #pragma unroll
        for (int m = 0; m < 4; ++m) acc1[m][n] = f32x4{b, b, b, b};
    }
    #pragma unroll
    for (int ks = 0; ks < 3; ++ks) {
        s16x8 af[4];
        #pragma unroll
        for (int m = 0; m < 4; ++m)
            af[m] = *reinterpret_cast<const s16x8*>(&x1b[(m*16 + lc)*XB_STR + ks*32 + lg*8]);
        #pragma unroll
        for (int n = 0; n < 6; ++n) {
            s16x8 bf = *reinterpret_cast<const s16x8*>(&w1p[((w*6 + n)*3 + ks)*512 + l*8]);
            #pragma unroll
            for (int m = 0; m < 4; ++m)
                acc1[m][n] = __builtin_amdgcn_mfma_f32_16x16x32_bf16(af[m], bf, acc1[m][n], 0, 0, 0);
        }
    }

    #pragma unroll
    for (int m = 0; m < 4; ++m) {
        #pragma unroll
        for (int n = 0; n < 6; ++n) {
            int col = w*96 + n*16 + lc;
            #pragma unroll
            for (int r = 0; r < 4; ++r) {
                int row = m*16 + lg*4 + r;
                float a = acc1[m][n][r];
                float gel = 0.5f*a*(1.0f + erff(a*0.70710678118654752f));
                hb[row*H_STR + col] = f2bf(gel);
            }
        }
    }
    __syncthreads();

    f32x4 acc2[6];
    #pragma unroll
    for (int n = 0; n < 6; ++n) {
        float b = fc2_b[n*16 + lc];
        acc2[n] = f32x4{b, b, b, b};
    }
    #pragma unroll
    for (int ks = 0; ks < 12; ++ks) {
        s16x8 af = *reinterpret_cast<const s16x8*>(&hb[(w*16 + lc)*H_STR + ks*32 + lg*8]);
        #pragma unroll
        for (int n = 0; n < 6; ++n) {
            s16x8 bf = *reinterpret_cast<const s16x8*>(&w2p[(n*12 + ks)*512 + l*8]);
            acc2[n] = __builtin_amdgcn_mfma_f32_16x16x32_bf16(af, bf, acc2[n], 0, 0, 0);
        }
    }

    #pragma unroll
    for (int r = 0; r < 4; ++r) {
        float s = 0.f, sq = 0.f;
        #pragma unroll
        for (int n = 0; n < 6; ++n) { float v = acc2[n][r]; s += v; sq += v*v; }
        #pragma unroll
        for (int m = 1; m < 16; m <<= 1) { s += __shfl_xor(s, m, 64); sq += __shfl_xor(sq, m, 64); }
        float mu  = s * (1.0f/DIM);
        float var = sq * (1.0f/DIM) - mu*mu;
        float rs  = rsqrtf(fmaxf(var, 0.f) + 1e-5f);
        int t = w*16 + lg*4 + r;
        #pragma unroll
        for (int n = 0; n < 6; ++n) {
            int c = n*16 + lc;
            out[base + t*DIM + c] = x1v[n][r] + (acc2[n][r] - mu)*rs*g2[c] + b2v[c];
        }
    }
}

extern "C" void kernel_launch(void* const* d_in, const int* in_sizes, int n_in,
                              void* d_out, int out_size, void* d_ws, size_t ws_size,
                              hipStream_t stream) {
    const float* x      = (const float*)d_in[0];
    const float* qkv_w  = (const float*)d_in[1];
    const float* q_bias = (const float*)d_in[2];
    const float* v_bias = (const float*)d_in[3];
    const float* lscale = (const float*)d_in[4];
    const float* cpb_w1 = (const float*)d_in[5];
    const float* cpb_b1 = (const float*)d_in[6];
    const float* cpb_w2 = (const float*)d_in[7];
    const float* proj_w = (const float*)d_in[8];
    const float* proj_b = (const float*)d_in[9];
    const float* n1g    = (const float*)d_in[10];
    const float* n1b    = (const float*)d_in[11];
    const float* fc1_w  = (const float*)d_in[12];
    const float* fc1_b  = (const float*)d_in[13];
    const float* fc2_w  = (const float*)d_in[14];
    const float* fc2_b  = (const float*)d_in[15];
    const float* n2g    = (const float*)d_in[16];
    const float* n2b    = (const float*)d_in[17];
    float* out = (float*)d_out;

    char* wsb = (char*)d_ws;
    float* tbl  = (float*)wsb;                         // 343*3 f32
    float* rpb  = (float*)(wsb + 8192);                // 3*64*64 f32 (48KB)
    short* w1p  = (short*)(wsb + 65536);               // 36864 bf16
    short* w2p  = (short*)(wsb + 65536 + 73728);       // 36864 bf16
    short* qkvp = (short*)(wsb + 65536 + 147456);      // 27648 bf16
    short* projp= qkvp + 27648;                        // 9216 bf16

    cpb_table_kernel<<<343, 256, 0, stream>>>(cpb_w1, cpb_b1, cpb_w2, tbl);
    rpb_kernel<<<192, 64, 0, stream>>>(tbl, rpb);
    pack_mlp_w<<<144, 256, 0, stream>>>(fc1_w, fc2_w, w1p, w2p);
    pack_attn_w<<<108, 256, 0, stream>>>(qkv_w, proj_w, qkvp, projp);
    attn_mfma_kernel<<<2*NWIN, 256, 0, stream>>>(x, qkvp, q_bias, v_bias, lscale,
                                                 projp, proj_b, rpb, out);
    mlp_mfma_kernel<<<(2*RES*RES*RES)/64, 256, 0, stream>>>(x, out, n1g, n1b,
                                                            w1p, fc1_b, w2p, fc2_b,
                                                            n2g, n2b, out);
}

// Round 5
// 194.021 us; speedup vs baseline: 32.7210x; 1.2707x over previous
//
#include <hip/hip_runtime.h>
#include <math.h>

#define RES   48
#define WS    4
#define SSH   2
#define DIM   96
#define HEADS 3
#define HD    32
#define NTOK  64
#define NWAX  12
#define NWIN  (NWAX*NWAX*NWAX)   // 1728

#define TSTR 104   // bf16 stride for token-major tiles (quad stride 13, odd)
#define VSTR 72
#define PSTR 72
#define H_STR 392  // bf16 stride for h (quad stride 49, odd)

typedef float f32x4 __attribute__((ext_vector_type(4)));
typedef short s16x8 __attribute__((ext_vector_type(8)));

__device__ __forceinline__ short f2bf(float f) {
    unsigned u = __builtin_bit_cast(unsigned, f);
    u = (u + 0x7FFFu + ((u >> 16) & 1u)) >> 16;
    return (short)u;
}
__device__ __forceinline__ float bf2f(short s) {
    unsigned u = ((unsigned)(unsigned short)s) << 16;
    return __builtin_bit_cast(float, u);
}
__device__ __forceinline__ float gelu_f(float a) {
    // a * sigmoid(2*0.7978845608*(a + 0.044715 a^3)); max abs err ~3e-4 vs exact
    float z = a*(1.5957691216057308f + 0.07135481627159927f*a*a);
    return a / (1.0f + __expf(-z));
}
__device__ __forceinline__ int region(int g) {
    return (g < RES - WS) ? 0 : ((g < RES - SSH) ? 1 : 2);
}

// ---------------- merged prep: cpb table + pack mlp weights + pack attn weights ----------------
__global__ void prep_kernel(const float* __restrict__ cw1, const float* __restrict__ cb1,
                            const float* __restrict__ cw2,
                            const float* __restrict__ fc1_w, const float* __restrict__ fc2_w,
                            const float* __restrict__ qkv_w, const float* __restrict__ proj_w,
                            float* __restrict__ tbl,
                            short* __restrict__ w1p, short* __restrict__ w2p,
                            short* __restrict__ qkvp, short* __restrict__ projp) {
    int bid = blockIdx.x;
    if (bid < 343) {
        __shared__ float hid[512];
        int ti = bid;
        int a = ti / 49, b = (ti / 7) % 7, c = ti % 7;
        float comp[3] = {(float)(a - 3), (float)(b - 3), (float)(c - 3)};
        float f[3];
        #pragma unroll
        for (int k = 0; k < 3; ++k) {
            float u = (comp[k] / 3.0f) * 8.0f;
            float s = (u > 0.f) ? 1.f : ((u < 0.f) ? -1.f : 0.f);
            f[k] = s * log2f(fabsf(u) + 1.0f) * (1.0f / 3.0f);
        }
        for (int j = threadIdx.x; j < 512; j += blockDim.x) {
            float acc = cb1[j] + f[0]*cw1[j*3+0] + f[1]*cw1[j*3+1] + f[2]*cw1[j*3+2];
            hid[j] = fmaxf(acc, 0.f);
        }
        __syncthreads();
        int tid = threadIdx.x;
        if (tid < 192) {
            int h = tid >> 6, lane = tid & 63;
            float p = 0.f;
            for (int j = lane; j < 512; j += 64) p += cw2[h*512 + j] * hid[j];
            #pragma unroll
            for (int off = 32; off; off >>= 1) p += __shfl_down(p, off, 64);
            if (lane == 0) tbl[ti*3 + h] = p;
        }
    } else if (bid < 343 + 144) {
        int i = (bid - 343)*256 + threadIdx.x;
        if (i >= 36864) return;
        {
            int o = i / 96, c = i - o*96;
            int tile = (o >> 4)*3 + (c >> 5);
            int lane = ((c >> 3) & 3)*16 + (o & 15);
            w1p[tile*512 + lane*8 + (c & 7)] = f2bf(fc1_w[i]);
        }
        {
            int co = i / 384, oo = i - co*384;
            int tile = (co >> 4)*12 + (oo >> 5);
            int lane = ((oo >> 3) & 3)*16 + (co & 15);
            w2p[tile*512 + lane*8 + (oo & 7)] = f2bf(fc2_w[i]);
        }
    } else {
        int i = (bid - 487)*256 + threadIdx.x;
        if (i < 288*96) {
            int o = i / 96, c = i - o*96;
            int tile = (o >> 4)*3 + (c >> 5);
            int lane = ((c >> 3) & 3)*16 + (o & 15);
            qkvp[tile*512 + lane*8 + (c & 7)] = f2bf(qkv_w[i]);
        }
        if (i < 96*96) {
            int co = i / 96, k = i - co*96;
            int tile = (co >> 4)*3 + (k >> 5);
            int lane = ((k >> 3) & 3)*16 + (co & 15);
            projp[tile*512 + lane*8 + (k & 7)] = f2bf(proj_w[i]);
        }
    }
}

// ---------------- rpb[h][i][j] = 16*sigmoid(tbl[rpi(i,j)][h]) ----------------
__global__ void rpb_kernel(const float* __restrict__ tbl, float* __restrict__ rpb) {
    int bi = blockIdx.x;                 // h*64 + i
    int h = bi >> 6, i = bi & 63;
    int j = threadIdx.x;
    int hi = i >> 4, wi = (i >> 2) & 3, di = i & 3;
    int hj = j >> 4, wj = (j >> 2) & 3, dj = j & 3;
    int idx = (hi - hj + 3)*49 + (wi - wj + 3)*7 + (di - dj + 3);
    float v = tbl[idx*3 + h];
    rpb[(h*64 + i)*64 + j] = 16.0f / (1.0f + expf(-v));
}

// ---------------- fully fused SwinV2 block kernel ----------------
__global__ __launch_bounds__(256, 2)
void swin_fused_kernel(const float* __restrict__ x, const short* __restrict__ qkvp,
                       const float* __restrict__ q_bias, const float* __restrict__ v_bias,
                       const float* __restrict__ logit_scale,
                       const short* __restrict__ projp, const float* __restrict__ proj_b,
                       const float* __restrict__ rpb,
                       const float* __restrict__ g1, const float* __restrict__ b1v,
                       const short* __restrict__ w1p, const float* __restrict__ fc1_b,
                       const short* __restrict__ w2p, const float* __restrict__ fc2_b,
                       const float* __restrict__ g2, const float* __restrict__ b2v,
                       float* __restrict__ out) {
    __shared__ __align__(16) char pool[64768];
    int*   xbase = (int*)(pool + 0);            // 256
    int*   cnt_s = (int*)(pool + 256);          // 256
    float* knorm = (float*)(pool + 512);        // 768  -> 1280
    short* x_s   = (short*)(pool + 1280);       // 64*104*2 = 13312 -> 14592
    short* q_s   = (short*)(pool + 14592);      // 13312 -> 27904
    short* k_s   = (short*)(pool + 27904);      // 13312 -> 41216
    short* vT    = (short*)(pool + 41216);      // 96*72*2 = 13824 -> 55040
    short* p_s   = (short*)(pool + 55040);      // 64*72*2 = 9216 -> 64256
    // MLP-phase aliases (valid after S5):
    short* x1b   = x_s;                          // stride TSTR
    short* hb    = (short*)(pool + 14592);      // 64*392*2 = 50176 -> 64768
    short* ao_s  = q_s;

    int tid = threadIdx.x;
    int l   = tid & 63;
    int w   = __builtin_amdgcn_readfirstlane(tid >> 6);
    int lc  = l & 15;
    int lg  = l >> 4;

    int wid = blockIdx.x;
    int b   = wid / NWIN;
    int rem = wid - b*NWIN;
    int wh = rem / (NWAX*NWAX);
    int ww = (rem / NWAX) % NWAX;
    int wd = rem % NWAX;

    if (tid < NTOK) {
        int t = tid;
        int lh = t >> 4, lw = (t >> 2) & 3, ld = t & 3;
        int gh = wh*WS + lh, gw = ww*WS + lw, gd = wd*WS + ld;
        int sh = (gh + SSH) % RES, sw = (gw + SSH) % RES, sd = (gd + SSH) % RES;
        xbase[t] = (((b*RES + sh)*RES + sw)*RES + sd)*DIM;
        cnt_s[t] = region(gh)*9 + region(gw)*3 + region(gd);
    }
    __syncthreads();   // S1

    // stage x -> bf16
    for (int idx = tid; idx < NTOK*12; idx += 256) {
        int r = idx / 12, g = idx - r*12;
        const float* src = x + xbase[r] + g*8;
        float4 a = *reinterpret_cast<const float4*>(src);
        float4 c = *reinterpret_cast<const float4*>(src + 4);
        s16x8 v;
        v[0]=f2bf(a.x); v[1]=f2bf(a.y); v[2]=f2bf(a.z); v[3]=f2bf(a.w);
        v[4]=f2bf(c.x); v[5]=f2bf(c.y); v[6]=f2bf(c.z); v[7]=f2bf(c.w);
        *reinterpret_cast<s16x8*>(&x_s[r*TSTR + g*8]) = v;
    }
    __syncthreads();   // S2

    // ---- QKV GEMM: 18 N-tiles round-robin over waves ----
    {
        s16x8 af[3][4];
        #pragma unroll
        for (int ks = 0; ks < 3; ++ks)
            #pragma unroll
            for (int m = 0; m < 4; ++m)
                af[ks][m] = *reinterpret_cast<const s16x8*>(&x_s[(m*16+lc)*TSTR + ks*32 + lg*8]);

        for (int nt = w; nt < 18; nt += 4) {
            int col = nt*16 + lc;
            float bias = 0.f;
            if (nt < 6) bias = q_bias[col];
            else if (nt >= 12) bias = v_bias[col - 192];
            f32x4 C[4];
            #pragma unroll
            for (int m = 0; m < 4; ++m) C[m] = f32x4{bias, bias, bias, bias};
            #pragma unroll
            for (int ks = 0; ks < 3; ++ks) {
                s16x8 bf = *reinterpret_cast<const s16x8*>(&qkvp[(nt*3+ks)*512 + l*8]);
                #pragma unroll
                for (int m = 0; m < 4; ++m)
                    C[m] = __builtin_amdgcn_mfma_f32_16x16x32_bf16(af[ks][m], bf, C[m], 0, 0, 0);
            }
            if (nt < 6) {
                #pragma unroll
                for (int m = 0; m < 4; ++m)
                    #pragma unroll
                    for (int r = 0; r < 4; ++r)
                        q_s[(m*16+lg*4+r)*TSTR + col] = f2bf(C[m][r]);
            } else if (nt < 12) {
                #pragma unroll
                for (int m = 0; m < 4; ++m)
                    #pragma unroll
                    for (int r = 0; r < 4; ++r)
                        k_s[(m*16+lg*4+r)*TSTR + col - 96] = f2bf(C[m][r]);
            } else {
                #pragma unroll
                for (int m = 0; m < 4; ++m)
                    #pragma unroll
                    for (int r = 0; r < 4; ++r)
                        vT[(col-192)*VSTR + m*16+lg*4+r] = f2bf(C[m][r]);
            }
        }
    }
    __syncthreads();   // S3

    // ---- norms: knorm table; q normalized+scaled in place ----
    if (tid < 192) {
        int h = tid >> 6, i = tid & 63;
        float n = 0.f;
        #pragma unroll
        for (int c = 0; c < 4; ++c) {
            s16x8 v = *reinterpret_cast<const s16x8*>(&k_s[i*TSTR + h*32 + c*8]);
            #pragma unroll
            for (int e = 0; e < 8; ++e) { float f = bf2f(v[e]); n += f*f; }
        }
        knorm[h*64 + i] = 1.0f / fmaxf(sqrtf(n), 1e-12f);

        s16x8 qv[4];
        float qn = 0.f;
        #pragma unroll
        for (int c = 0; c < 4; ++c) {
            qv[c] = *reinterpret_cast<const s16x8*>(&q_s[i*TSTR + h*32 + c*8]);
            #pragma unroll
            for (int e = 0; e < 8; ++e) { float f = bf2f(qv[c][e]); qn += f*f; }
        }
        float sc = __expf(fminf(logit_scale[h], 4.605170185988092f));
        float qr = sc / fmaxf(sqrtf(qn), 1e-12f);
        #pragma unroll
        for (int c = 0; c < 4; ++c) {
            s16x8 o;
            #pragma unroll
            for (int e = 0; e < 8; ++e) o[e] = f2bf(bf2f(qv[c][e]) * qr);
            *reinterpret_cast<s16x8*>(&q_s[i*TSTR + h*32 + c*8]) = o;
        }
    }
    __syncthreads();   // S4 — attention waves free-run below

    // ---- QK^T ----
    f32x4 sc_[3][4];
    {
        s16x8 aq[3];
        #pragma unroll
        for (int h = 0; h < 3; ++h)
            aq[h] = *reinterpret_cast<const s16x8*>(&q_s[(w*16+lc)*TSTR + h*32 + lg*8]);
        #pragma unroll
        for (int h = 0; h < 3; ++h)
            #pragma unroll
            for (int nt = 0; nt < 4; ++nt) {
                s16x8 bk = *reinterpret_cast<const s16x8*>(&k_s[(nt*16+lc)*TSTR + h*32 + lg*8]);
                sc_[h][nt] = __builtin_amdgcn_mfma_f32_16x16x32_bf16(aq[h], bk, f32x4{0.f,0.f,0.f,0.f}, 0, 0, 0);
            }
    }

    int ci[4];
    #pragma unroll
    for (int r = 0; r < 4; ++r) ci[r] = cnt_s[w*16 + lg*4 + r];
    int cjv[4];
    #pragma unroll
    for (int nt = 0; nt < 4; ++nt) cjv[nt] = cnt_s[nt*16 + lc];

    // ---- per head: softmax -> P -> PV -> staged attn-out ----
    #pragma unroll
    for (int h = 0; h < 3; ++h) {
        #pragma unroll
        for (int nt = 0; nt < 4; ++nt) {
            float kn = knorm[h*64 + nt*16 + lc];
            int cj = cjv[nt];
            #pragma unroll
            for (int r = 0; r < 4; ++r) {
                int row = w*16 + lg*4 + r;
                float s = sc_[h][nt][r]*kn + rpb[(h*64 + row)*64 + nt*16 + lc];
                if (ci[r] != cj) s -= 100.0f;
                sc_[h][nt][r] = s;
            }
        }
        float linv[4];
        #pragma unroll
        for (int r = 0; r < 4; ++r) {
            float mm = fmaxf(fmaxf(sc_[h][0][r], sc_[h][1][r]), fmaxf(sc_[h][2][r], sc_[h][3][r]));
            #pragma unroll
            for (int msk = 1; msk < 16; msk <<= 1) mm = fmaxf(mm, __shfl_xor(mm, msk, 64));
            float ll = 0.f;
            #pragma unroll
            for (int nt = 0; nt < 4; ++nt) {
                float ee = __expf(sc_[h][nt][r] - mm);
                sc_[h][nt][r] = ee;
                ll += ee;
            }
            #pragma unroll
            for (int msk = 1; msk < 16; msk <<= 1) ll += __shfl_xor(ll, msk, 64);
            linv[r] = 1.0f / ll;
        }
        #pragma unroll
        for (int nt = 0; nt < 4; ++nt)
            #pragma unroll
            for (int r = 0; r < 4; ++r)
                p_s[(w*16+lg*4+r)*PSTR + nt*16 + lc] = f2bf(sc_[h][nt][r]);

        f32x4 o0 = {0.f,0.f,0.f,0.f}, o1 = {0.f,0.f,0.f,0.f};
        #pragma unroll
        for (int ks = 0; ks < 2; ++ks) {
            s16x8 ap = *reinterpret_cast<const s16x8*>(&p_s[(w*16+lc)*PSTR + ks*32 + lg*8]);
            s16x8 b0 = *reinterpret_cast<const s16x8*>(&vT[(h*32 + lc)*VSTR + ks*32 + lg*8]);
            s16x8 b1 = *reinterpret_cast<const s16x8*>(&vT[(h*32 + 16 + lc)*VSTR + ks*32 + lg*8]);
            o0 = __builtin_amdgcn_mfma_f32_16x16x32_bf16(ap, b0, o0, 0, 0, 0);
            o1 = __builtin_amdgcn_mfma_f32_16x16x32_bf16(ap, b1, o1, 0, 0, 0);
        }
        #pragma unroll
        for (int r = 0; r < 4; ++r) {
            ao_s[(w*16+lg*4+r)*TSTR + h*32 + lc]      = f2bf(o0[r]*linv[r]);
            ao_s[(w*16+lg*4+r)*TSTR + h*32 + 16 + lc] = f2bf(o1[r]*linv[r]);
        }
    }

    // ---- proj (own-wave rows); keep result in registers ----
    float yv[6][4];
    {
        s16x8 aa[3];
        #pragma unroll
        for (int ks = 0; ks < 3; ++ks)
            aa[ks] = *reinterpret_cast<const s16x8*>(&ao_s[(w*16+lc)*TSTR + ks*32 + lg*8]);
        #pragma unroll
        for (int nt = 0; nt < 6; ++nt) {
            float bias = proj_b[nt*16 + lc];
            f32x4 C = f32x4{bias, bias, bias, bias};
            #pragma unroll
            for (int ks = 0; ks < 3; ++ks) {
                s16x8 bf = *reinterpret_cast<const s16x8*>(&projp[(nt*3+ks)*512 + l*8]);
                C = __builtin_amdgcn_mfma_f32_16x16x32_bf16(aa[ks], bf, C, 0, 0, 0);
            }
            #pragma unroll
            for (int r = 0; r < 4; ++r) yv[nt][r] = C[r];
        }
    }
    __syncthreads();   // S5 — attn LDS dead; MLP aliases become valid

    // ---- LN1 + residual (x from bf16 x_s, same addresses then overwritten by x1b) ----
    float x1v[6][4];
    #pragma unroll
    for (int r = 0; r < 4; ++r) {
        float s = 0.f, sq = 0.f;
        #pragma unroll
        for (int n = 0; n < 6; ++n) { float v = yv[n][r]; s += v; sq += v*v; }
        #pragma unroll
        for (int m = 1; m < 16; m <<= 1) { s += __shfl_xor(s, m, 64); sq += __shfl_xor(sq, m, 64); }
        float mu  = s * (1.0f/DIM);
        float var = sq * (1.0f/DIM) - mu*mu;
        float rs  = rsqrtf(fmaxf(var, 0.f) + 1e-5f);
        int t = w*16 + lg*4 + r;
        #pragma unroll
        for (int n = 0; n < 6; ++n) {
            int c = n*16 + lc;
            float xf = bf2f(x_s[t*TSTR + c]);
            float v = xf + (yv[n][r] - mu)*rs*g1[c] + b1v[c];
            x1v[n][r] = v;
            x1b[t*TSTR + c] = f2bf(v);
        }
    }
    __syncthreads();   // S6 — x1b complete

    // ---- fc1 + gelu -> hb ----
    {
        f32x4 acc1[4][6];
        #pragma unroll
        for (int n = 0; n < 6; ++n) {
            float bb = fc1_b[w*96 + n*16 + lc];
            #pragma unroll
            for (int m = 0; m < 4; ++m) acc1[m][n] = f32x4{bb, bb, bb, bb};
        }
        #pragma unroll
        for (int ks = 0; ks < 3; ++ks) {
            s16x8 af[4];
            #pragma unroll
            for (int m = 0; m < 4; ++m)
                af[m] = *reinterpret_cast<const s16x8*>(&x1b[(m*16 + lc)*TSTR + ks*32 + lg*8]);
            #pragma unroll
            for (int n = 0; n < 6; ++n) {
                s16x8 bf = *reinterpret_cast<const s16x8*>(&w1p[((w*6 + n)*3 + ks)*512 + l*8]);
                #pragma unroll
                for (int m = 0; m < 4; ++m)
                    acc1[m][n] = __builtin_amdgcn_mfma_f32_16x16x32_bf16(af[m], bf, acc1[m][n], 0, 0, 0);
            }
        }
        #pragma unroll
        for (int m = 0; m < 4; ++m) {
            #pragma unroll
            for (int n = 0; n < 6; ++n) {
                int col = w*96 + n*16 + lc;
                #pragma unroll
                for (int r = 0; r < 4; ++r) {
                    int row = m*16 + lg*4 + r;
                    hb[row*H_STR + col] = f2bf(gelu_f(acc1[m][n][r]));
                }
            }
        }
    }
    __syncthreads();   // S7 — hb complete

    // ---- fc2 + LN2 + residual + write ----
    {
        f32x4 acc2[6];
        #pragma unroll
        for (int n = 0; n < 6; ++n) {
            float bb = fc2_b[n*16 + lc];
            acc2[n] = f32x4{bb, bb, bb, bb};
        }
        #pragma unroll
        for (int ks = 0; ks < 12; ++ks) {
            s16x8 af = *reinterpret_cast<const s16x8*>(&hb[(w*16 + lc)*H_STR + ks*32 + lg*8]);
            #pragma unroll
            for (int n = 0; n < 6; ++n) {
                s16x8 bf = *reinterpret_cast<const s16x8*>(&w2p[(n*12 + ks)*512 + l*8]);
                acc2[n] = __builtin_amdgcn_mfma_f32_16x16x32_bf16(af, bf, acc2[n], 0, 0, 0);
            }
        }
        #pragma unroll
        for (int r = 0; r < 4; ++r) {
            float s = 0.f, sq = 0.f;
            #pragma unroll
            for (int n = 0; n < 6; ++n) { float v = acc2[n][r]; s += v; sq += v*v; }
            #pragma unroll
            for (int m = 1; m < 16; m <<= 1) { s += __shfl_xor(s, m, 64); sq += __shfl_xor(sq, m, 64); }
            float mu  = s * (1.0f/DIM);
            float var = sq * (1.0f/DIM) - mu*mu;
            float rs  = rsqrtf(fmaxf(var, 0.f) + 1e-5f);
            int t = w*16 + lg*4 + r;
            int xb = xbase[t];
            #pragma unroll
            for (int n = 0; n < 6; ++n) {
                int c = n*16 + lc;
                out[xb + c] = x1v[n][r] + (acc2[n][r] - mu)*rs*g2[c] + b2v[c];
            }
        }
    }
}

extern "C" void kernel_launch(void* const* d_in, const int* in_sizes, int n_in,
                              void* d_out, int out_size, void* d_ws, size_t ws_size,
                              hipStream_t stream) {
    const float* x      = (const float*)d_in[0];
    const float* qkv_w  = (const float*)d_in[1];
    const float* q_bias = (const float*)d_in[2];
    const float* v_bias = (const float*)d_in[3];
    const float* lscale = (const float*)d_in[4];
    const float* cpb_w1 = (const float*)d_in[5];
    const float* cpb_b1 = (const float*)d_in[6];
    const float* cpb_w2 = (const float*)d_in[7];
    const float* proj_w = (const float*)d_in[8];
    const float* proj_b = (const float*)d_in[9];
    const float* n1g    = (const float*)d_in[10];
    const float* n1b    = (const float*)d_in[11];
    const float* fc1_w  = (const float*)d_in[12];
    const float* fc1_b  = (const float*)d_in[13];
    const float* fc2_w  = (const float*)d_in[14];
    const float* fc2_b  = (const float*)d_in[15];
    const float* n2g    = (const float*)d_in[16];
    const float* n2b    = (const float*)d_in[17];
    float* out = (float*)d_out;

    char* wsb = (char*)d_ws;
    float* tbl  = (float*)wsb;                         // 343*3 f32
    float* rpb  = (float*)(wsb + 8192);                // 3*64*64 f32 (48KB)
    short* w1p  = (short*)(wsb + 65536);               // 36864 bf16
    short* w2p  = (short*)(wsb + 65536 + 73728);       // 36864 bf16
    short* qkvp = (short*)(wsb + 65536 + 147456);      // 27648 bf16
    short* projp= qkvp + 27648;                        // 9216 bf16

    prep_kernel<<<595, 256, 0, stream>>>(cpb_w1, cpb_b1, cpb_w2, fc1_w, fc2_w,
                                         qkv_w, proj_w, tbl, w1p, w2p, qkvp, projp);
    rpb_kernel<<<192, 64, 0, stream>>>(tbl, rpb);
    swin_fused_kernel<<<2*NWIN, 256, 0, stream>>>(x, qkvp, q_bias, v_bias, lscale,
                                                  projp, proj_b, rpb,
                                                  n1g, n1b, w1p, fc1_b, w2p, fc2_b,
                                                  n2g, n2b, out);
}